// Round 1
// baseline (567.796 us; speedup 1.0000x reference)
//
#include <hip/hip_runtime.h>
#include <hip/hip_bf16.h>

// GravNetConv: N=16384 points, C_IN=128, S=4 latent dims, P=32 msg dims, K=16 NN, C_OUT=128.
// Pipeline: [k1] s (fp64-acc) + h projections -> [k2] exact 16-NN brute force, j-split x8,
// buffered-filter selection -> [k3] merge chunks + weighted mean/max aggregation ->
// [k4a] weight transpose -> [k4] out = x@W1^T + agg@W2^T + b2 (fp32 VALU).
// Workspace use: ~24.1 MB.

#define NPTS 16384
#define CIN  128
#define SD   4
#define PD   32
#define KNN  16
#define COUT 128
#define JS   8          // j-chunks in knn scan
#define TJ   (NPTS/JS)  // 2048 j per chunk
#define BUF  24         // filter buffer slots per thread (LDS), padded stride 25
#define FLTMAX 3.4028234663852886e+38f

// ---- workspace byte offsets ----
#define WS_S4     0            // N * float4            = 256 KB
#define WS_H      (1u<<19)     // N * 32 f32            = 2 MB   (starts 512K)
#define WS_CE     (4u<<20)     // [128][N] f32          = 8 MB
#define WS_CJ     (12u<<20)    // [128][N] i32          = 8 MB
#define WS_AGG    (20u<<20)    // [N][64] f32           = 4 MB
#define WS_WT     (24u<<20)    // [192][128] f32        = 96 KB

// ---------------- Kernel 1: s (fp64 accumulate) and h projections ----------------
__global__ __launch_bounds__(256) void k1_proj(
    const float* __restrict__ x, const float* __restrict__ Ws, const float* __restrict__ bs,
    const float* __restrict__ Wh, const float* __restrict__ bh,
    float4* __restrict__ s4, float* __restrict__ h) {
  __shared__ float lws[SD*CIN];
  __shared__ float lwh[PD*CIN];
  __shared__ float lbs[SD];
  __shared__ float lbh[PD];
  __shared__ float lx[256*36];   // 256 rows x 32 floats, stride 36 (16B-aligned, bank-rotated)
  const int t = threadIdx.x;
  for (int i2 = t; i2 < SD*CIN; i2 += 256) lws[i2] = Ws[i2];
  for (int i2 = t; i2 < PD*CIN; i2 += 256) lwh[i2] = Wh[i2];
  if (t < SD) lbs[t] = bs[t];
  if (t < PD) lbh[t] = bh[t];
  const int row0 = blockIdx.x * 256;
  double sacc[SD] = {0.0, 0.0, 0.0, 0.0};
  float  hacc[PD];
#pragma unroll
  for (int p = 0; p < PD; ++p) hacc[p] = 0.f;
  for (int kc = 0; kc < 4; ++kc) {
    __syncthreads();
#pragma unroll
    for (int q = 0; q < 8; ++q) {
      int fi = q*256 + t;            // 0..2047 float4 units
      int r  = fi >> 3, kq = fi & 7;
      float4 v = *(const float4*)&x[(size_t)(row0 + r)*CIN + kc*32 + kq*4];
      *(float4*)&lx[r*36 + kq*4] = v;
    }
    __syncthreads();
#pragma unroll
    for (int k4 = 0; k4 < 8; ++k4) {
      float4 xv = *(const float4*)&lx[t*36 + k4*4];
      int kg = kc*32 + k4*4;
#pragma unroll
      for (int p = 0; p < SD; ++p) {
        float4 wv = *(const float4*)&lws[p*CIN + kg];
        sacc[p] = fma((double)xv.x, (double)wv.x, sacc[p]);
        sacc[p] = fma((double)xv.y, (double)wv.y, sacc[p]);
        sacc[p] = fma((double)xv.z, (double)wv.z, sacc[p]);
        sacc[p] = fma((double)xv.w, (double)wv.w, sacc[p]);
      }
#pragma unroll
      for (int p = 0; p < PD; ++p) {
        float4 wv = *(const float4*)&lwh[p*CIN + kg];
        hacc[p] = fmaf(xv.x, wv.x, fmaf(xv.y, wv.y, fmaf(xv.z, wv.z, fmaf(xv.w, wv.w, hacc[p]))));
      }
    }
  }
  const int i = row0 + t;
  float s0 = (float)(sacc[0] + (double)lbs[0]);
  float s1 = (float)(sacc[1] + (double)lbs[1]);
  float s2 = (float)(sacc[2] + (double)lbs[2]);
  float s3 = (float)(sacc[3] + (double)lbs[3]);
  s4[i] = make_float4(s0, s1, s2, s3);
#pragma unroll
  for (int p = 0; p < PD; ++p) h[(size_t)i*PD + p] = hacc[p] + lbh[p];
}

// ---------------- Kernel 2: brute-force 16-NN scan over one j-chunk ----------------
__global__ __launch_bounds__(256) void k2_knn(
    const float4* __restrict__ s4,
    float* __restrict__ cand_e, int* __restrict__ cand_j) {
  __shared__ int lbuf[256*25];    // per-thread 24-slot buffer, stride 25 (bank-rotate)
  const int t  = threadIdx.x;
  const int ib = blockIdx.x & 63;
  const int jc = blockIdx.x >> 6;
  const int i  = ib*256 + t;
  const int jbase = jc * TJ;
  const float4 si = s4[i];
  const float4* __restrict__ sb = s4 + jbase;   // uniform base: lanes read same j -> scalarizable

  float val[KNN]; int vid[KNN];
#pragma unroll
  for (int q = 0; q < KNN; ++q) { val[q] = FLTMAX; vid[q] = 0; }
  float cmax = FLTMAX; int cpos = 0; int cnt = 0;

  auto compact = [&]() {
    for (int u = 0; u < cnt; ++u) {
      int jj = lbuf[t*25 + u];
      float4 pj = sb[jj];
      float dx = si.x - pj.x, dy = si.y - pj.y, dz = si.z - pj.z, dw = si.w - pj.w;
      float e = fmaf(dx, dx, fmaf(dy, dy, fmaf(dz, dz, dw*dw)));
      if (e < cmax) {
#pragma unroll
        for (int q = 0; q < KNN; ++q) if (q == cpos) { val[q] = e; vid[q] = jj; }
        cmax = val[0]; cpos = 0;
#pragma unroll
        for (int q = 1; q < KNN; ++q) { if (val[q] > cmax) { cmax = val[q]; cpos = q; } }
      }
    }
    cnt = 0;
  };

  for (int ob = 0; ob < TJ/8; ++ob) {
#pragma unroll
    for (int u = 0; u < 8; ++u) {
      int jj = ob*8 + u;
      float4 pj = sb[jj];
      float dx = si.x - pj.x, dy = si.y - pj.y, dz = si.z - pj.z, dw = si.w - pj.w;
      float e = fmaf(dx, dx, fmaf(dy, dy, fmaf(dz, dz, dw*dw)));
      if (e < cmax) { lbuf[t*25 + cnt] = jj; cnt++; }   // cheap filter; exact test at compaction
    }
    if (__any(cnt > BUF - 8)) compact();
  }
  compact();

#pragma unroll
  for (int q = 0; q < KNN; ++q) {
    int c = jc*KNN + q;
    cand_e[(size_t)c*NPTS + i] = val[q];
    cand_j[(size_t)c*NPTS + i] = vid[q] + jbase;
  }
}

// ---------------- Kernel 3: merge candidate chunks + aggregate messages ----------------
__global__ __launch_bounds__(256) void k3_merge(
    const float* __restrict__ h,
    const float* __restrict__ cand_e, const int* __restrict__ cand_j,
    float* __restrict__ agg) {
  const int t = threadIdx.x;
  const int i = blockIdx.x*256 + t;
  float val[KNN]; int vid[KNN];
#pragma unroll
  for (int q = 0; q < KNN; ++q) { val[q] = FLTMAX; vid[q] = 0; }
  float cmax = FLTMAX; int cpos = 0;
  for (int c = 0; c < JS*KNN; ++c) {          // ascending chunk => ascending j (tie pref: low idx)
    float e = cand_e[(size_t)c*NPTS + i];
    int   j = cand_j[(size_t)c*NPTS + i];
    if (e < cmax) {
#pragma unroll
      for (int q = 0; q < KNN; ++q) if (q == cpos) { val[q] = e; vid[q] = j; }
      cmax = val[0]; cpos = 0;
#pragma unroll
      for (int q = 1; q < KNN; ++q) { if (val[q] > cmax) { cmax = val[q]; cpos = q; } }
    }
  }
  float msum[PD], mmax[PD];
#pragma unroll
  for (int p = 0; p < PD; ++p) { msum[p] = 0.f; mmax[p] = -FLTMAX; }
#pragma unroll 1
  for (int q = 0; q < KNN; ++q) {
    int j = vid[q];
    float w = __expf(-10.f * val[q]);          // val is exact direct-form d2, same as reference
#pragma unroll
    for (int p4 = 0; p4 < PD/4; ++p4) {
      float4 hv = *(const float4*)&h[(size_t)j*PD + p4*4];
      float m0 = hv.x * w, m1 = hv.y * w, m2 = hv.z * w, m3 = hv.w * w;
      msum[p4*4+0] += m0; mmax[p4*4+0] = fmaxf(mmax[p4*4+0], m0);
      msum[p4*4+1] += m1; mmax[p4*4+1] = fmaxf(mmax[p4*4+1], m1);
      msum[p4*4+2] += m2; mmax[p4*4+2] = fmaxf(mmax[p4*4+2], m2);
      msum[p4*4+3] += m3; mmax[p4*4+3] = fmaxf(mmax[p4*4+3], m3);
    }
  }
#pragma unroll
  for (int p = 0; p < PD; ++p) {
    agg[(size_t)i*64 + p]      = msum[p] * 0.0625f;   // mean = /16
    agg[(size_t)i*64 + 32 + p] = mmax[p];
  }
}

// ---------------- Kernel 4a: pack/transpose weights: wT[k][c], k<128 from W1, k>=128 from W2 ----
__global__ __launch_bounds__(256) void k4a_wt(
    const float* __restrict__ W1, const float* __restrict__ W2, float* __restrict__ wT) {
  int idx = blockIdx.x*256 + threadIdx.x;
  if (idx >= 192*COUT) return;
  int k = idx >> 7, c = idx & 127;
  float v = (k < 128) ? W1[(size_t)c*128 + k] : W2[(size_t)c*64 + (k - 128)];
  wT[(size_t)k*COUT + c] = v;
}

// ---------------- Kernel 4: out = x@W1^T + agg@W2^T + b2 ----------------
__global__ __launch_bounds__(256) void k4_out(
    const float* __restrict__ x, const float* __restrict__ agg,
    const float* __restrict__ wT, const float* __restrict__ b2,
    float* __restrict__ out) {
  __shared__ float xa[16*192];     // [r][k] fused x|agg, 12.3 KB
  __shared__ float red[16*256];    // partial-sum exchange, 16 KB
  const int t = threadIdx.x;
  const int row0 = blockIdx.x * 16;
  for (int idx = t; idx < 16*CIN; idx += 256) {
    int r = idx >> 7, k = idx & 127;
    xa[r*192 + k] = x[(size_t)(row0 + r)*CIN + k];
  }
  for (int idx = t; idx < 16*64; idx += 256) {
    int r = idx >> 6, k = idx & 63;
    xa[r*192 + 128 + k] = agg[(size_t)(row0 + r)*64 + k];
  }
  __syncthreads();
  const int c = t & 127, kh = t >> 7;
  float acc[16];
#pragma unroll
  for (int r = 0; r < 16; ++r) acc[r] = 0.f;
  for (int k4 = 0; k4 < 24; ++k4) {
    int ko = kh*96 + k4*4;
    float w0 = wT[(size_t)(ko+0)*COUT + c];   // coalesced
    float w1 = wT[(size_t)(ko+1)*COUT + c];
    float w2 = wT[(size_t)(ko+2)*COUT + c];
    float w3 = wT[(size_t)(ko+3)*COUT + c];
#pragma unroll
    for (int r = 0; r < 16; ++r) {
      float4 xv = *(const float4*)&xa[r*192 + ko];   // broadcast
      acc[r] = fmaf(w0, xv.x, fmaf(w1, xv.y, fmaf(w2, xv.z, fmaf(w3, xv.w, acc[r]))));
    }
  }
#pragma unroll
  for (int r = 0; r < 16; ++r) red[r*256 + t] = acc[r];
  __syncthreads();
  if (kh == 0) {
    float bias = b2[c];
#pragma unroll
    for (int r = 0; r < 16; ++r) {
      float v = red[r*256 + t] + red[r*256 + t + 128] + bias;
      out[(size_t)(row0 + r)*COUT + c] = v;
    }
  }
}

extern "C" void kernel_launch(void* const* d_in, const int* in_sizes, int n_in,
                              void* d_out, int out_size, void* d_ws, size_t ws_size,
                              hipStream_t stream) {
  const float* x  = (const float*)d_in[0];
  const float* Ws = (const float*)d_in[1];
  const float* bs = (const float*)d_in[2];
  const float* Wh = (const float*)d_in[3];
  const float* bh = (const float*)d_in[4];
  const float* W1 = (const float*)d_in[5];
  const float* W2 = (const float*)d_in[6];
  const float* b2 = (const float*)d_in[7];
  float* out = (float*)d_out;

  char* ws = (char*)d_ws;
  float4* s4   = (float4*)(ws + WS_S4);
  float*  h    = (float*) (ws + WS_H);
  float*  ce   = (float*) (ws + WS_CE);
  int*    cj   = (int*)   (ws + WS_CJ);
  float*  agg  = (float*) (ws + WS_AGG);
  float*  wT   = (float*) (ws + WS_WT);

  k1_proj<<<NPTS/256, 256, 0, stream>>>(x, Ws, bs, Wh, bh, s4, h);
  k2_knn<<<64*JS, 256, 0, stream>>>(s4, ce, cj);
  k3_merge<<<NPTS/256, 256, 0, stream>>>(h, ce, cj, agg);
  k4a_wt<<<(192*COUT + 255)/256, 256, 0, stream>>>(W1, W2, wT);
  k4_out<<<NPTS/16, 256, 0, stream>>>(x, agg, wT, b2, out);
}

// Round 2
// 567.279 us; speedup vs baseline: 1.0009x; 1.0009x over previous
//
#include <hip/hip_runtime.h>
#include <hip/hip_bf16.h>

// GravNetConv: N=16384, C_IN=128, S=4, P=32, K=16, C_OUT=128.
// [k1] s (fp64-acc) + h projections -> [k2] 16-NN, 16 j-chunks, LDS-staged tile,
// M=2 queries/thread, buffered-filter selection, u16 ids only ->
// [k3] merge (4 thr/point, exact d2 recompute) + weighted mean/max aggregation ->
// [k4a] weight transpose -> [k4] out = x@W1^T + agg@W2^T + b2.
// Workspace: 16.1 MB.

#define NPTS 16384
#define CIN  128
#define SD   4
#define PD   32
#define KNN  16
#define COUT 128
#define JS   16         // j-chunks
#define TJ   (NPTS/JS)  // 1024 j per chunk
#define FLTMAX 3.4028234663852886e+38f

typedef float v2f __attribute__((ext_vector_type(2)));

// ---- workspace byte offsets ----
#define WS_S4     0            // N * float4 = 256 KB
#define WS_H      0x40000      // N * 32 f32 = 2 MB
#define WS_CJ     0x400000     // [256][N] u16 = 8 MB
#define WS_AGG    0xC00000     // [N][64] f32 = 4 MB
#define WS_WT     0x1000000    // [192][128] f32 = 96 KB

__device__ __forceinline__ float d2f(const float4 a, const float4 b) {
  v2f d0 = {a.x - b.x, a.y - b.y};
  v2f d1 = {a.z - b.z, a.w - b.w};
  v2f pr = d0*d0 + d1*d1;       // contracts to pk_mul + pk_fma
  return pr.x + pr.y;
}

// ---------------- Kernel 1: s (fp64 accumulate) and h projections ----------------
__global__ __launch_bounds__(256) void k1_proj(
    const float* __restrict__ x, const float* __restrict__ Ws, const float* __restrict__ bs,
    const float* __restrict__ Wh, const float* __restrict__ bh,
    float4* __restrict__ s4, float* __restrict__ h) {
  __shared__ float lws[SD*CIN];
  __shared__ float lwh[PD*CIN];
  __shared__ float lbs[SD];
  __shared__ float lbh[PD];
  __shared__ float lx[256*36];
  const int t = threadIdx.x;
  for (int i2 = t; i2 < SD*CIN; i2 += 256) lws[i2] = Ws[i2];
  for (int i2 = t; i2 < PD*CIN; i2 += 256) lwh[i2] = Wh[i2];
  if (t < SD) lbs[t] = bs[t];
  if (t < PD) lbh[t] = bh[t];
  const int row0 = blockIdx.x * 256;
  double sacc[SD] = {0.0, 0.0, 0.0, 0.0};
  float  hacc[PD];
#pragma unroll
  for (int p = 0; p < PD; ++p) hacc[p] = 0.f;
  for (int kc = 0; kc < 4; ++kc) {
    __syncthreads();
#pragma unroll
    for (int q = 0; q < 8; ++q) {
      int fi = q*256 + t;
      int r  = fi >> 3, kq = fi & 7;
      float4 v = *(const float4*)&x[(size_t)(row0 + r)*CIN + kc*32 + kq*4];
      *(float4*)&lx[r*36 + kq*4] = v;
    }
    __syncthreads();
#pragma unroll
    for (int k4 = 0; k4 < 8; ++k4) {
      float4 xv = *(const float4*)&lx[t*36 + k4*4];
      int kg = kc*32 + k4*4;
#pragma unroll
      for (int p = 0; p < SD; ++p) {
        float4 wv = *(const float4*)&lws[p*CIN + kg];
        sacc[p] = fma((double)xv.x, (double)wv.x, sacc[p]);
        sacc[p] = fma((double)xv.y, (double)wv.y, sacc[p]);
        sacc[p] = fma((double)xv.z, (double)wv.z, sacc[p]);
        sacc[p] = fma((double)xv.w, (double)wv.w, sacc[p]);
      }
#pragma unroll
      for (int p = 0; p < PD; ++p) {
        float4 wv = *(const float4*)&lwh[p*CIN + kg];
        hacc[p] = fmaf(xv.x, wv.x, fmaf(xv.y, wv.y, fmaf(xv.z, wv.z, fmaf(xv.w, wv.w, hacc[p]))));
      }
    }
  }
  const int i = row0 + t;
  float s0 = (float)(sacc[0] + (double)lbs[0]);
  float s1 = (float)(sacc[1] + (double)lbs[1]);
  float s2 = (float)(sacc[2] + (double)lbs[2]);
  float s3 = (float)(sacc[3] + (double)lbs[3]);
  s4[i] = make_float4(s0, s1, s2, s3);
#pragma unroll
  for (int p = 0; p < PD; ++p) h[(size_t)i*PD + p] = hacc[p] + lbh[p];
}

// ---------------- Kernel 2: 16-NN scan, LDS-staged chunk, 2 queries/thread ----------------
__global__ __launch_bounds__(256) void k2_knn(
    const float4* __restrict__ s4, unsigned short* __restrict__ cand_j) {
  __shared__ float4 tile[TJ];       // 16 KB
  __shared__ int    lbuf[256*33];   // 2 x 16-slot filter buffers, 33.8 KB
  const int t  = threadIdx.x;
  const int ib = blockIdx.x & 31;   // 32 i-blocks x 512 queries
  const int jc = blockIdx.x >> 5;   // 16 chunks
  const int jbase = jc * TJ;
#pragma unroll
  for (int g = 0; g < 4; ++g) tile[g*256 + t] = s4[jbase + g*256 + t];
  const int ia = ib*256 + t;
  const int ic = ia + 8192;
  const float4 sa = s4[ia];
  const float4 sc = s4[ic];
  __syncthreads();

  float va[KNN], vb[KNN]; int ja[KNN], jb[KNN];
#pragma unroll
  for (int q = 0; q < KNN; ++q) { va[q] = FLTMAX; ja[q] = 0; vb[q] = FLTMAX; jb[q] = 0; }
  float cma = FLTMAX, cmb = FLTMAX;
  int cpa = 0, cpb = 0, ca = 0, cb = 0;

  auto insertA = [&](float e, int jj) {
#pragma unroll
    for (int q = 0; q < KNN; ++q) if (q == cpa) { va[q] = e; ja[q] = jj; }
    cma = va[0]; cpa = 0;
#pragma unroll
    for (int q = 1; q < KNN; ++q) { if (va[q] > cma) { cma = va[q]; cpa = q; } }
  };
  auto insertB = [&](float e, int jj) {
#pragma unroll
    for (int q = 0; q < KNN; ++q) if (q == cpb) { vb[q] = e; jb[q] = jj; }
    cmb = vb[0]; cpb = 0;
#pragma unroll
    for (int q = 1; q < KNN; ++q) { if (vb[q] > cmb) { cmb = vb[q]; cpb = q; } }
  };
  auto compactA = [&]() {
    for (int u = 0; u < ca; ++u) {
      int jj = lbuf[t*33 + u];
      float e = d2f(sa, tile[jj]);
      if (e < cma) insertA(e, jj);
    }
    ca = 0;
  };
  auto compactB = [&]() {
    for (int u = 0; u < cb; ++u) {
      int jj = lbuf[t*33 + 16 + u];
      float e = d2f(sc, tile[jj]);
      if (e < cmb) insertB(e, jj);
    }
    cb = 0;
  };

  for (int ob = 0; ob < TJ/8; ++ob) {
#pragma unroll
    for (int u = 0; u < 8; ++u) {
      int jj = ob*8 + u;
      float4 p = tile[jj];
      float ea = d2f(sa, p);
      float eb = d2f(sc, p);
      if (ea < cma) { lbuf[t*33 + ca] = jj; ++ca; }
      if (eb < cmb) { lbuf[t*33 + 16 + cb] = jj; ++cb; }
    }
    if (__any(ca > 8)) compactA();
    if (__any(cb > 8)) compactB();
  }
  compactA(); compactB();

#pragma unroll
  for (int q = 0; q < KNN; ++q) {
    int c = jc*KNN + q;
    cand_j[(size_t)c*NPTS + ia] = (unsigned short)(ja[q] + jbase);
    cand_j[(size_t)c*NPTS + ic] = (unsigned short)(jb[q] + jbase);
  }
}

// ---------------- Kernel 3: merge 256 candidates -> top16, aggregate messages ----------------
__global__ __launch_bounds__(256) void k3_merge(
    const float4* __restrict__ s4, const float4* __restrict__ h4,
    const unsigned short* __restrict__ cand_j, float* __restrict__ agg) {
  __shared__ float le[64*67];   // 17.2 KB (stride 67: conflict-free)
  __shared__ int   lj[64*67];   // 17.2 KB
  const int t  = threadIdx.x;
  const int il = t & 63, tq = t >> 6;
  const int i  = blockIdx.x*64 + il;
  const float4 si = s4[i];

  float val[KNN]; int vid[KNN];
#pragma unroll
  for (int q = 0; q < KNN; ++q) { val[q] = FLTMAX; vid[q] = 0; }
  float cmax = FLTMAX; int cpos = 0;
  for (int u = 0; u < 64; ++u) {
    int c = tq*64 + u;                       // thread covers 4 consecutive chunks
    int j = cand_j[(size_t)c*NPTS + i];
    float e = d2f(si, s4[j]);
    if (e < cmax) {
#pragma unroll
      for (int q = 0; q < KNN; ++q) if (q == cpos) { val[q] = e; vid[q] = j; }
      cmax = val[0]; cpos = 0;
#pragma unroll
      for (int q = 1; q < KNN; ++q) { if (val[q] > cmax) { cmax = val[q]; cpos = q; } }
    }
  }
#pragma unroll
  for (int q = 0; q < KNN; ++q) {
    le[il*67 + tq*16 + q] = val[q];
    lj[il*67 + tq*16 + q] = vid[q];
  }
  __syncthreads();
  if (t < 64) {                              // wave 0: merge 64 -> 16 per point
    float mv[KNN]; int mj[KNN];
#pragma unroll
    for (int q = 0; q < KNN; ++q) { mv[q] = FLTMAX; mj[q] = 0; }
    float cm2 = FLTMAX; int cp2 = 0;
    for (int u = 0; u < 64; ++u) {
      float e = le[t*67 + u];
      int   j = lj[t*67 + u];
      if (e < cm2) {
#pragma unroll
        for (int q = 0; q < KNN; ++q) if (q == cp2) { mv[q] = e; mj[q] = j; }
        cm2 = mv[0]; cp2 = 0;
#pragma unroll
        for (int q = 1; q < KNN; ++q) { if (mv[q] > cm2) { cm2 = mv[q]; cp2 = q; } }
      }
    }
#pragma unroll
    for (int q = 0; q < KNN; ++q) {          // overwrite own region: (w, j)
      le[t*67 + q] = __expf(-10.f * mv[q]);
      lj[t*67 + q] = mj[q];
    }
  }
  __syncthreads();
  float ms[8], mm[8];
#pragma unroll
  for (int p = 0; p < 8; ++p) { ms[p] = 0.f; mm[p] = -FLTMAX; }
#pragma unroll 1
  for (int q = 0; q < KNN; ++q) {
    float w = le[il*67 + q];
    int   j = lj[il*67 + q];
    float4 a = h4[(size_t)j*8 + tq*2];
    float4 b = h4[(size_t)j*8 + tq*2 + 1];
    float m0 = a.x*w, m1 = a.y*w, m2 = a.z*w, m3 = a.w*w;
    float m4 = b.x*w, m5 = b.y*w, m6 = b.z*w, m7 = b.w*w;
    ms[0] += m0; mm[0] = fmaxf(mm[0], m0);
    ms[1] += m1; mm[1] = fmaxf(mm[1], m1);
    ms[2] += m2; mm[2] = fmaxf(mm[2], m2);
    ms[3] += m3; mm[3] = fmaxf(mm[3], m3);
    ms[4] += m4; mm[4] = fmaxf(mm[4], m4);
    ms[5] += m5; mm[5] = fmaxf(mm[5], m5);
    ms[6] += m6; mm[6] = fmaxf(mm[6], m6);
    ms[7] += m7; mm[7] = fmaxf(mm[7], m7);
  }
  float4 o0 = make_float4(ms[0], ms[1], ms[2], ms[3]);
  float4 o1 = make_float4(ms[4], ms[5], ms[6], ms[7]);
  o0.x *= 0.0625f; o0.y *= 0.0625f; o0.z *= 0.0625f; o0.w *= 0.0625f;
  o1.x *= 0.0625f; o1.y *= 0.0625f; o1.z *= 0.0625f; o1.w *= 0.0625f;
  *(float4*)&agg[(size_t)i*64 + tq*8]      = o0;
  *(float4*)&agg[(size_t)i*64 + tq*8 + 4]  = o1;
  *(float4*)&agg[(size_t)i*64 + 32 + tq*8]     = make_float4(mm[0], mm[1], mm[2], mm[3]);
  *(float4*)&agg[(size_t)i*64 + 32 + tq*8 + 4] = make_float4(mm[4], mm[5], mm[6], mm[7]);
}

// ---------------- Kernel 4a: pack/transpose weights ----------------
__global__ __launch_bounds__(256) void k4a_wt(
    const float* __restrict__ W1, const float* __restrict__ W2, float* __restrict__ wT) {
  int idx = blockIdx.x*256 + threadIdx.x;
  if (idx >= 192*COUT) return;
  int k = idx >> 7, c = idx & 127;
  float v = (k < 128) ? W1[(size_t)c*128 + k] : W2[(size_t)c*64 + (k - 128)];
  wT[(size_t)k*COUT + c] = v;
}

// ---------------- Kernel 4: out = x@W1^T + agg@W2^T + b2 ----------------
__global__ __launch_bounds__(256) void k4_out(
    const float* __restrict__ x, const float* __restrict__ agg,
    const float* __restrict__ wT, const float* __restrict__ b2,
    float* __restrict__ out) {
  __shared__ float xa[16*192];
  __shared__ float red[16*256];
  const int t = threadIdx.x;
  const int row0 = blockIdx.x * 16;
  for (int idx = t; idx < 16*CIN; idx += 256) {
    int r = idx >> 7, k = idx & 127;
    xa[r*192 + k] = x[(size_t)(row0 + r)*CIN + k];
  }
  for (int idx = t; idx < 16*64; idx += 256) {
    int r = idx >> 6, k = idx & 63;
    xa[r*192 + 128 + k] = agg[(size_t)(row0 + r)*64 + k];
  }
  __syncthreads();
  const int c = t & 127, kh = t >> 7;
  float acc[16];
#pragma unroll
  for (int r = 0; r < 16; ++r) acc[r] = 0.f;
  for (int k4 = 0; k4 < 24; ++k4) {
    int ko = kh*96 + k4*4;
    float w0 = wT[(size_t)(ko+0)*COUT + c];
    float w1 = wT[(size_t)(ko+1)*COUT + c];
    float w2 = wT[(size_t)(ko+2)*COUT + c];
    float w3 = wT[(size_t)(ko+3)*COUT + c];
#pragma unroll
    for (int r = 0; r < 16; ++r) {
      float4 xv = *(const float4*)&xa[r*192 + ko];
      acc[r] = fmaf(w0, xv.x, fmaf(w1, xv.y, fmaf(w2, xv.z, fmaf(w3, xv.w, acc[r]))));
    }
  }
#pragma unroll
  for (int r = 0; r < 16; ++r) red[r*256 + t] = acc[r];
  __syncthreads();
  if (kh == 0) {
    float bias = b2[c];
#pragma unroll
    for (int r = 0; r < 16; ++r) {
      float v = red[r*256 + t] + red[r*256 + t + 128] + bias;
      out[(size_t)(row0 + r)*COUT + c] = v;
    }
  }
}

extern "C" void kernel_launch(void* const* d_in, const int* in_sizes, int n_in,
                              void* d_out, int out_size, void* d_ws, size_t ws_size,
                              hipStream_t stream) {
  const float* x  = (const float*)d_in[0];
  const float* Ws = (const float*)d_in[1];
  const float* bs = (const float*)d_in[2];
  const float* Wh = (const float*)d_in[3];
  const float* bh = (const float*)d_in[4];
  const float* W1 = (const float*)d_in[5];
  const float* W2 = (const float*)d_in[6];
  const float* b2 = (const float*)d_in[7];
  float* out = (float*)d_out;

  char* ws = (char*)d_ws;
  float4*         s4  = (float4*)(ws + WS_S4);
  float*          h   = (float*) (ws + WS_H);
  unsigned short* cj  = (unsigned short*)(ws + WS_CJ);
  float*          agg = (float*) (ws + WS_AGG);
  float*          wT  = (float*) (ws + WS_WT);

  k1_proj<<<NPTS/256, 256, 0, stream>>>(x, Ws, bs, Wh, bh, s4, h);
  k2_knn<<<512, 256, 0, stream>>>(s4, cj);
  k3_merge<<<NPTS/64, 256, 0, stream>>>(s4, (const float4*)h, cj, agg);
  k4a_wt<<<(192*COUT + 255)/256, 256, 0, stream>>>(W1, W2, wT);
  k4_out<<<NPTS/16, 256, 0, stream>>>(x, agg, wT, b2, out);
}

// Round 3
// 507.156 us; speedup vs baseline: 1.1196x; 1.1185x over previous
//
#include <hip/hip_runtime.h>
#include <hip/hip_bf16.h>

// GravNetConv: N=16384, C_IN=128, S=4, P=32, K=16, C_OUT=128.
// Mask path: [k1] proj -> [k2a] per-query threshold (16th-NN over 1024 sampled j) ->
// [k2b] full N^2 scan -> bitmask (2 VALU/pair, no divergence) -> [k3_recover] exact
// top-16 from mask bits + weighted mean/max aggregation -> [k4a/k4] output GEMM.
// Fallback path (ws_size < 41MB): round-2 kernels (proven).

#define NPTS 16384
#define CIN  128
#define SD   4
#define PD   32
#define KNN  16
#define COUT 128
#define FLTMAX 3.4028234663852886e+38f

typedef float v2f __attribute__((ext_vector_type(2)));
typedef unsigned int uint;

// ---- shared offsets (both paths) ----
#define WS_S4     0            // N * float4 = 256 KB
#define WS_H      0x40000      // N * 32 f32 = 2 MB
// ---- mask-path offsets ----
#define WS_THR    0x240000     // 4 * N f32 = 256 KB
#define WS_AGG_M  0x280000     // [N][64] f32 = 4 MB
#define WS_WT_M   0x680000     // [192][128] f32 = 96 KB
#define WS_MASK   0x700000     // 128 chunks * N * 4 words u32 = 32 MB
#define WS_NEED_M 0x2700000    // 40.9 MB
// ---- fallback offsets (round-2 layout) ----
#define WS_CJ_F   0x400000     // [256][N] u16 = 8 MB
#define WS_AGG_F  0xC00000
#define WS_WT_F   0x1000000
#define JS   16
#define TJF  (NPTS/JS)

__device__ __forceinline__ float d2f(const float4 a, const float4 b) {
  v2f d0 = {a.x - b.x, a.y - b.y};
  v2f d1 = {a.z - b.z, a.w - b.w};
  v2f pr = d0*d0 + d1*d1;
  return pr.x + pr.y;
}

// ---------------- Kernel 1: s (fp64 accumulate) and h projections ----------------
__global__ __launch_bounds__(256) void k1_proj(
    const float* __restrict__ x, const float* __restrict__ Ws, const float* __restrict__ bs,
    const float* __restrict__ Wh, const float* __restrict__ bh,
    float4* __restrict__ s4, float* __restrict__ h) {
  __shared__ float lws[SD*CIN];
  __shared__ float lwh[PD*CIN];
  __shared__ float lbs[SD];
  __shared__ float lbh[PD];
  __shared__ float lx[256*36];
  const int t = threadIdx.x;
  for (int i2 = t; i2 < SD*CIN; i2 += 256) lws[i2] = Ws[i2];
  for (int i2 = t; i2 < PD*CIN; i2 += 256) lwh[i2] = Wh[i2];
  if (t < SD) lbs[t] = bs[t];
  if (t < PD) lbh[t] = bh[t];
  const int row0 = blockIdx.x * 256;
  double sacc[SD] = {0.0, 0.0, 0.0, 0.0};
  float  hacc[PD];
#pragma unroll
  for (int p = 0; p < PD; ++p) hacc[p] = 0.f;
  for (int kc = 0; kc < 4; ++kc) {
    __syncthreads();
#pragma unroll
    for (int q = 0; q < 8; ++q) {
      int fi = q*256 + t;
      int r  = fi >> 3, kq = fi & 7;
      float4 v = *(const float4*)&x[(size_t)(row0 + r)*CIN + kc*32 + kq*4];
      *(float4*)&lx[r*36 + kq*4] = v;
    }
    __syncthreads();
#pragma unroll
    for (int k4 = 0; k4 < 8; ++k4) {
      float4 xv = *(const float4*)&lx[t*36 + k4*4];
      int kg = kc*32 + k4*4;
#pragma unroll
      for (int p = 0; p < SD; ++p) {
        float4 wv = *(const float4*)&lws[p*CIN + kg];
        sacc[p] = fma((double)xv.x, (double)wv.x, sacc[p]);
        sacc[p] = fma((double)xv.y, (double)wv.y, sacc[p]);
        sacc[p] = fma((double)xv.z, (double)wv.z, sacc[p]);
        sacc[p] = fma((double)xv.w, (double)wv.w, sacc[p]);
      }
#pragma unroll
      for (int p = 0; p < PD; ++p) {
        float4 wv = *(const float4*)&lwh[p*CIN + kg];
        hacc[p] = fmaf(xv.x, wv.x, fmaf(xv.y, wv.y, fmaf(xv.z, wv.z, fmaf(xv.w, wv.w, hacc[p]))));
      }
    }
  }
  const int i = row0 + t;
  float s0 = (float)(sacc[0] + (double)lbs[0]);
  float s1 = (float)(sacc[1] + (double)lbs[1]);
  float s2 = (float)(sacc[2] + (double)lbs[2]);
  float s3 = (float)(sacc[3] + (double)lbs[3]);
  s4[i] = make_float4(s0, s1, s2, s3);
#pragma unroll
  for (int p = 0; p < PD; ++p) h[(size_t)i*PD + p] = hacc[p] + lbh[p];
}

// ---------------- Kernel 2a: per-query threshold = 16th-NN d2 over a 256-j sample ----------------
// grid 256 = 64 query-groups x 4 sample quarters; t_i (k2b) = min over quarters.
__global__ __launch_bounds__(256) void k2a_thresh(
    const float4* __restrict__ s4, float* __restrict__ thrq) {
  __shared__ float4 tile[256];
  const int t = threadIdx.x, b = blockIdx.x;
  const int qg = b >> 2, r = b & 3;
  const int q = qg*256 + t;
  const int jbase = r*4096 + (qg & 15)*256;
  tile[t] = s4[jbase + t];
  const float4 sq = s4[q];
  __syncthreads();
  float val[KNN];
#pragma unroll
  for (int u = 0; u < KNN; ++u) val[u] = d2f(sq, tile[u]);
  float cmax = val[0]; int cpos = 0;
#pragma unroll
  for (int u = 1; u < KNN; ++u) { if (val[u] > cmax) { cmax = val[u]; cpos = u; } }
  for (int j = KNN; j < 256; ++j) {
    float e = d2f(sq, tile[j]);
    if (e < cmax) {
#pragma unroll
      for (int u = 0; u < KNN; ++u) if (u == cpos) val[u] = e;
      cmax = val[0]; cpos = 0;
#pragma unroll
      for (int u = 1; u < KNN; ++u) { if (val[u] > cmax) { cmax = val[u]; cpos = u; } }
    }
  }
  thrq[r*NPTS + q] = cmax;
}

// ---------------- Kernel 2b: full scan -> bitmask. M=8 queries/thread, 128-j chunks --------------
// mask layout chunk-major: word[(c*16384 + q)*4 + w], bit b of word w <-> j = c*128 + w*32 + b.
__global__ __launch_bounds__(256) void k2b_mask(
    const float4* __restrict__ s4, const float* __restrict__ thrq, uint* __restrict__ maskw) {
  __shared__ float4 tile[128];
  const int t  = threadIdx.x;
  const int c  = blockIdx.x >> 3;   // 128 chunks
  const int ig = blockIdx.x & 7;    // 8 query groups of 2048
  if (t < 128) tile[t] = s4[c*128 + t];
  const int q0 = ig*2048 + t;
  float4 sq[8]; float thr[8];
#pragma unroll
  for (int m = 0; m < 8; ++m) {
    int q = q0 + m*256;
    sq[m] = s4[q];
    float t0 = thrq[q], t1 = thrq[NPTS + q], t2 = thrq[2*NPTS + q], t3 = thrq[3*NPTS + q];
    thr[m] = fminf(fminf(t0, t1), fminf(t2, t3)) * 1.000001f;
  }
  __syncthreads();
#pragma unroll 1
  for (int w = 0; w < 4; ++w) {
    uint msk[8];
#pragma unroll
    for (int m = 0; m < 8; ++m) msk[m] = 0u;
#pragma unroll
    for (int bit = 31; bit >= 0; --bit) {
      float4 p = tile[w*32 + bit];
#pragma unroll
      for (int m = 0; m < 8; ++m) {
        msk[m] = msk[m] + msk[m] + (d2f(sq[m], p) <= thr[m] ? 1u : 0u);  // v_cmp + addc
      }
    }
#pragma unroll
    for (int m = 0; m < 8; ++m) {
      int q = q0 + m*256;
      maskw[((size_t)c*NPTS + q)*4 + w] = msk[m];
    }
  }
}

// ---------------- Kernel 3: recover exact top-16 from mask + aggregate ----------------
// 8 threads/query: thread tq scans chunks [tq*16, tq*16+16), local top-16, LDS merge, aggregate.
__global__ __launch_bounds__(256) void k3_recover(
    const float4* __restrict__ s4, const float4* __restrict__ h4,
    const uint4* __restrict__ maskw, float* __restrict__ agg) {
  __shared__ float le[32*132];
  __shared__ int   lj[32*132];
  const int t = threadIdx.x;
  const int ql = t >> 3, tq = t & 7;
  const int q = blockIdx.x*32 + ql;
  const float4 sq = s4[q];
  float val[KNN]; int vid[KNN];
#pragma unroll
  for (int u = 0; u < KNN; ++u) { val[u] = FLTMAX; vid[u] = 0; }
  float cmax = FLTMAX; int cpos = 0;

  for (int cc = 0; cc < 16; ++cc) {
    const int c = tq*16 + cc;
    uint4 mw = maskw[(size_t)c*NPTS + q];
    uint wv[4] = {mw.x, mw.y, mw.z, mw.w};
#pragma unroll 1
    for (int w = 0; w < 4; ++w) {
      uint bits = wv[w];
      while (bits) {
        int b = __builtin_ctz(bits); bits &= bits - 1;
        int j = c*128 + w*32 + b;
        float e = d2f(sq, s4[j]);
        if (e < cmax) {
#pragma unroll
          for (int u = 0; u < KNN; ++u) if (u == cpos) { val[u] = e; vid[u] = j; }
          cmax = val[0]; cpos = 0;
#pragma unroll
          for (int u = 1; u < KNN; ++u) { if (val[u] > cmax) { cmax = val[u]; cpos = u; } }
        }
      }
    }
  }
#pragma unroll
  for (int u = 0; u < KNN; ++u) {
    le[ql*132 + tq*16 + u] = val[u];
    lj[ql*132 + tq*16 + u] = vid[u];
  }
  __syncthreads();
  if (tq == 0) {                       // merge 128 -> 16 (ascending tq => ascending j ranges)
    float mv[KNN]; int mj[KNN];
#pragma unroll
    for (int u = 0; u < KNN; ++u) { mv[u] = FLTMAX; mj[u] = 0; }
    float cm2 = FLTMAX; int cp2 = 0;
    for (int u = 0; u < 128; ++u) {
      float e = le[ql*132 + u];
      int   j = lj[ql*132 + u];
      if (e < cm2) {
#pragma unroll
        for (int v = 0; v < KNN; ++v) if (v == cp2) { mv[v] = e; mj[v] = j; }
        cm2 = mv[0]; cp2 = 0;
#pragma unroll
        for (int v = 1; v < KNN; ++v) { if (mv[v] > cm2) { cm2 = mv[v]; cp2 = v; } }
      }
    }
#pragma unroll
    for (int u = 0; u < KNN; ++u) {
      le[ql*132 + u] = __expf(-10.f * mv[u]);
      lj[ql*132 + u] = mj[u];
    }
  }
  __syncthreads();
  float ms[4] = {0.f, 0.f, 0.f, 0.f};
  float mm[4] = {-FLTMAX, -FLTMAX, -FLTMAX, -FLTMAX};
#pragma unroll 1
  for (int u = 0; u < KNN; ++u) {
    float w = le[ql*132 + u];
    int   j = lj[ql*132 + u];
    float4 hv = h4[(size_t)j*8 + tq];
    float m0 = hv.x*w, m1 = hv.y*w, m2 = hv.z*w, m3 = hv.w*w;
    ms[0] += m0; mm[0] = fmaxf(mm[0], m0);
    ms[1] += m1; mm[1] = fmaxf(mm[1], m1);
    ms[2] += m2; mm[2] = fmaxf(mm[2], m2);
    ms[3] += m3; mm[3] = fmaxf(mm[3], m3);
  }
  *(float4*)&agg[(size_t)q*64 + tq*4] =
      make_float4(ms[0]*0.0625f, ms[1]*0.0625f, ms[2]*0.0625f, ms[3]*0.0625f);
  *(float4*)&agg[(size_t)q*64 + 32 + tq*4] = make_float4(mm[0], mm[1], mm[2], mm[3]);
}

// ================= Fallback path (round-2, proven) =================
__global__ __launch_bounds__(256) void k2_knn_fb(
    const float4* __restrict__ s4, unsigned short* __restrict__ cand_j) {
  __shared__ float4 tile[TJF];
  __shared__ int    lbuf[256*33];
  const int t  = threadIdx.x;
  const int ib = blockIdx.x & 31;
  const int jc = blockIdx.x >> 5;
  const int jbase = jc * TJF;
#pragma unroll
  for (int g = 0; g < 4; ++g) tile[g*256 + t] = s4[jbase + g*256 + t];
  const int ia = ib*256 + t;
  const int ic = ia + 8192;
  const float4 sa = s4[ia];
  const float4 sc = s4[ic];
  __syncthreads();
  float va[KNN], vb[KNN]; int ja[KNN], jb[KNN];
#pragma unroll
  for (int q = 0; q < KNN; ++q) { va[q] = FLTMAX; ja[q] = 0; vb[q] = FLTMAX; jb[q] = 0; }
  float cma = FLTMAX, cmb = FLTMAX;
  int cpa = 0, cpb = 0, ca = 0, cb = 0;
  auto insertA = [&](float e, int jj) {
#pragma unroll
    for (int q = 0; q < KNN; ++q) if (q == cpa) { va[q] = e; ja[q] = jj; }
    cma = va[0]; cpa = 0;
#pragma unroll
    for (int q = 1; q < KNN; ++q) { if (va[q] > cma) { cma = va[q]; cpa = q; } }
  };
  auto insertB = [&](float e, int jj) {
#pragma unroll
    for (int q = 0; q < KNN; ++q) if (q == cpb) { vb[q] = e; jb[q] = jj; }
    cmb = vb[0]; cpb = 0;
#pragma unroll
    for (int q = 1; q < KNN; ++q) { if (vb[q] > cmb) { cmb = vb[q]; cpb = q; } }
  };
  auto compactA = [&]() {
    for (int u = 0; u < ca; ++u) {
      int jj = lbuf[t*33 + u];
      float e = d2f(sa, tile[jj]);
      if (e < cma) insertA(e, jj);
    }
    ca = 0;
  };
  auto compactB = [&]() {
    for (int u = 0; u < cb; ++u) {
      int jj = lbuf[t*33 + 16 + u];
      float e = d2f(sc, tile[jj]);
      if (e < cmb) insertB(e, jj);
    }
    cb = 0;
  };
  for (int ob = 0; ob < TJF/8; ++ob) {
#pragma unroll
    for (int u = 0; u < 8; ++u) {
      int jj = ob*8 + u;
      float4 p = tile[jj];
      float ea = d2f(sa, p);
      float eb = d2f(sc, p);
      if (ea < cma) { lbuf[t*33 + ca] = jj; ++ca; }
      if (eb < cmb) { lbuf[t*33 + 16 + cb] = jj; ++cb; }
    }
    if (__any(ca > 8)) compactA();
    if (__any(cb > 8)) compactB();
  }
  compactA(); compactB();
#pragma unroll
  for (int q = 0; q < KNN; ++q) {
    int c = jc*KNN + q;
    cand_j[(size_t)c*NPTS + ia] = (unsigned short)(ja[q] + jbase);
    cand_j[(size_t)c*NPTS + ic] = (unsigned short)(jb[q] + jbase);
  }
}

__global__ __launch_bounds__(256) void k3_merge_fb(
    const float4* __restrict__ s4, const float4* __restrict__ h4,
    const unsigned short* __restrict__ cand_j, float* __restrict__ agg) {
  __shared__ float le[64*67];
  __shared__ int   lj[64*67];
  const int t  = threadIdx.x;
  const int il = t & 63, tq = t >> 6;
  const int i  = blockIdx.x*64 + il;
  const float4 si = s4[i];
  float val[KNN]; int vid[KNN];
#pragma unroll
  for (int q = 0; q < KNN; ++q) { val[q] = FLTMAX; vid[q] = 0; }
  float cmax = FLTMAX; int cpos = 0;
  for (int u = 0; u < 64; ++u) {
    int c = tq*64 + u;
    int j = cand_j[(size_t)c*NPTS + i];
    float e = d2f(si, s4[j]);
    if (e < cmax) {
#pragma unroll
      for (int q = 0; q < KNN; ++q) if (q == cpos) { val[q] = e; vid[q] = j; }
      cmax = val[0]; cpos = 0;
#pragma unroll
      for (int q = 1; q < KNN; ++q) { if (val[q] > cmax) { cmax = val[q]; cpos = q; } }
    }
  }
#pragma unroll
  for (int q = 0; q < KNN; ++q) {
    le[il*67 + tq*16 + q] = val[q];
    lj[il*67 + tq*16 + q] = vid[q];
  }
  __syncthreads();
  if (t < 64) {
    float mv[KNN]; int mj[KNN];
#pragma unroll
    for (int q = 0; q < KNN; ++q) { mv[q] = FLTMAX; mj[q] = 0; }
    float cm2 = FLTMAX; int cp2 = 0;
    for (int u = 0; u < 64; ++u) {
      float e = le[t*67 + u];
      int   j = lj[t*67 + u];
      if (e < cm2) {
#pragma unroll
        for (int q = 0; q < KNN; ++q) if (q == cp2) { mv[q] = e; mj[q] = j; }
        cm2 = mv[0]; cp2 = 0;
#pragma unroll
        for (int q = 1; q < KNN; ++q) { if (mv[q] > cm2) { cm2 = mv[q]; cp2 = q; } }
      }
    }
#pragma unroll
    for (int q = 0; q < KNN; ++q) {
      le[t*67 + q] = __expf(-10.f * mv[q]);
      lj[t*67 + q] = mj[q];
    }
  }
  __syncthreads();
  float ms[8], mm[8];
#pragma unroll
  for (int p = 0; p < 8; ++p) { ms[p] = 0.f; mm[p] = -FLTMAX; }
#pragma unroll 1
  for (int q = 0; q < KNN; ++q) {
    float w = le[il*67 + q];
    int   j = lj[il*67 + q];
    float4 a = h4[(size_t)j*8 + tq*2];
    float4 b = h4[(size_t)j*8 + tq*2 + 1];
    float m0 = a.x*w, m1 = a.y*w, m2 = a.z*w, m3 = a.w*w;
    float m4 = b.x*w, m5 = b.y*w, m6 = b.z*w, m7 = b.w*w;
    ms[0] += m0; mm[0] = fmaxf(mm[0], m0);
    ms[1] += m1; mm[1] = fmaxf(mm[1], m1);
    ms[2] += m2; mm[2] = fmaxf(mm[2], m2);
    ms[3] += m3; mm[3] = fmaxf(mm[3], m3);
    ms[4] += m4; mm[4] = fmaxf(mm[4], m4);
    ms[5] += m5; mm[5] = fmaxf(mm[5], m5);
    ms[6] += m6; mm[6] = fmaxf(mm[6], m6);
    ms[7] += m7; mm[7] = fmaxf(mm[7], m7);
  }
  float4 o0 = make_float4(ms[0]*0.0625f, ms[1]*0.0625f, ms[2]*0.0625f, ms[3]*0.0625f);
  float4 o1 = make_float4(ms[4]*0.0625f, ms[5]*0.0625f, ms[6]*0.0625f, ms[7]*0.0625f);
  *(float4*)&agg[(size_t)i*64 + tq*8]      = o0;
  *(float4*)&agg[(size_t)i*64 + tq*8 + 4]  = o1;
  *(float4*)&agg[(size_t)i*64 + 32 + tq*8]     = make_float4(mm[0], mm[1], mm[2], mm[3]);
  *(float4*)&agg[(size_t)i*64 + 32 + tq*8 + 4] = make_float4(mm[4], mm[5], mm[6], mm[7]);
}

// ---------------- Kernel 4a: pack/transpose weights ----------------
__global__ __launch_bounds__(256) void k4a_wt(
    const float* __restrict__ W1, const float* __restrict__ W2, float* __restrict__ wT) {
  int idx = blockIdx.x*256 + threadIdx.x;
  if (idx >= 192*COUT) return;
  int k = idx >> 7, c = idx & 127;
  float v = (k < 128) ? W1[(size_t)c*128 + k] : W2[(size_t)c*64 + (k - 128)];
  wT[(size_t)k*COUT + c] = v;
}

// ---------------- Kernel 4: out = x@W1^T + agg@W2^T + b2 ----------------
__global__ __launch_bounds__(256) void k4_out(
    const float* __restrict__ x, const float* __restrict__ agg,
    const float* __restrict__ wT, const float* __restrict__ b2,
    float* __restrict__ out) {
  __shared__ float xa[16*192];
  __shared__ float red[16*256];
  const int t = threadIdx.x;
  const int row0 = blockIdx.x * 16;
  for (int idx = t; idx < 16*CIN; idx += 256) {
    int r = idx >> 7, k = idx & 127;
    xa[r*192 + k] = x[(size_t)(row0 + r)*CIN + k];
  }
  for (int idx = t; idx < 16*64; idx += 256) {
    int r = idx >> 6, k = idx & 63;
    xa[r*192 + 128 + k] = agg[(size_t)(row0 + r)*64 + k];
  }
  __syncthreads();
  const int c = t & 127, kh = t >> 7;
  float acc[16];
#pragma unroll
  for (int r = 0; r < 16; ++r) acc[r] = 0.f;
  for (int k4 = 0; k4 < 24; ++k4) {
    int ko = kh*96 + k4*4;
    float w0 = wT[(size_t)(ko+0)*COUT + c];
    float w1 = wT[(size_t)(ko+1)*COUT + c];
    float w2 = wT[(size_t)(ko+2)*COUT + c];
    float w3 = wT[(size_t)(ko+3)*COUT + c];
#pragma unroll
    for (int r = 0; r < 16; ++r) {
      float4 xv = *(const float4*)&xa[r*192 + ko];
      acc[r] = fmaf(w0, xv.x, fmaf(w1, xv.y, fmaf(w2, xv.z, fmaf(w3, xv.w, acc[r]))));
    }
  }
#pragma unroll
  for (int r = 0; r < 16; ++r) red[r*256 + t] = acc[r];
  __syncthreads();
  if (kh == 0) {
    float bias = b2[c];
#pragma unroll
    for (int r = 0; r < 16; ++r) {
      float v = red[r*256 + t] + red[r*256 + t + 128] + bias;
      out[(size_t)(row0 + r)*COUT + c] = v;
    }
  }
}

extern "C" void kernel_launch(void* const* d_in, const int* in_sizes, int n_in,
                              void* d_out, int out_size, void* d_ws, size_t ws_size,
                              hipStream_t stream) {
  const float* x  = (const float*)d_in[0];
  const float* Ws = (const float*)d_in[1];
  const float* bs = (const float*)d_in[2];
  const float* Wh = (const float*)d_in[3];
  const float* bh = (const float*)d_in[4];
  const float* W1 = (const float*)d_in[5];
  const float* W2 = (const float*)d_in[6];
  const float* b2 = (const float*)d_in[7];
  float* out = (float*)d_out;

  char* ws = (char*)d_ws;
  float4* s4 = (float4*)(ws + WS_S4);
  float*  h  = (float*) (ws + WS_H);

  k1_proj<<<NPTS/256, 256, 0, stream>>>(x, Ws, bs, Wh, bh, s4, h);

  if (ws_size >= (size_t)WS_NEED_M) {
    float* thrq = (float*)(ws + WS_THR);
    float* agg  = (float*)(ws + WS_AGG_M);
    float* wT   = (float*)(ws + WS_WT_M);
    uint*  mw   = (uint*) (ws + WS_MASK);
    k2a_thresh<<<256, 256, 0, stream>>>(s4, thrq);
    k2b_mask<<<1024, 256, 0, stream>>>(s4, thrq, mw);
    k3_recover<<<NPTS/32, 256, 0, stream>>>(s4, (const float4*)h, (const uint4*)mw, agg);
    k4a_wt<<<(192*COUT + 255)/256, 256, 0, stream>>>(W1, W2, wT);
    k4_out<<<NPTS/16, 256, 0, stream>>>(x, agg, wT, b2, out);
  } else {
    unsigned short* cj = (unsigned short*)(ws + WS_CJ_F);
    float* agg = (float*)(ws + WS_AGG_F);
    float* wT  = (float*)(ws + WS_WT_F);
    k2_knn_fb<<<512, 256, 0, stream>>>(s4, cj);
    k3_merge_fb<<<NPTS/64, 256, 0, stream>>>(s4, (const float4*)h, cj, agg);
    k4a_wt<<<(192*COUT + 255)/256, 256, 0, stream>>>(W1, W2, wT);
    k4_out<<<NPTS/16, 256, 0, stream>>>(x, agg, wT, b2, out);
  }
}

// Round 4
// 413.518 us; speedup vs baseline: 1.3731x; 1.2264x over previous
//
#include <hip/hip_runtime.h>
#include <hip/hip_bf16.h>

// GravNetConv: N=16384, C_IN=128, S=4, P=32, K=16, C_OUT=128.
// Mask path: [k1] proj -> [k2a] sample threshold t1 -> [k2c] refined t2 (12-level count
// over 2048-subset, B bounded ~[128,244]) -> [k2b] full N^2 scan -> bitmask (t2) ->
// [k3_sel] phased recovery: bit-extract -> batched gathers -> reg top-16 -> 16-lane
// shfl tournament on exact (d2,j) keys, fused aggregation -> [k4a/k4_out2] GEMM
// (64x128 tile, 8x4 reg tile: LDS traffic 1.6GB -> 0.4GB).
// Fallback path (ws_size < 41MB): round-2 kernels.

#define NPTS 16384
#define CIN  128
#define SD   4
#define PD   32
#define KNN  16
#define COUT 128
#define FLTMAX 3.4028234663852886e+38f
#define RL   12        // k2c refinement levels
#define CCAP 48        // k3 per-thread candidate cap (16 thr/query)
#define CSTR 50        // LDS stride for cand (u16) -> conflict-free

typedef float v2f __attribute__((ext_vector_type(2)));
typedef unsigned int uint;

// ---- shared offsets (both paths) ----
#define WS_S4     0            // N * float4 = 256 KB
#define WS_H      0x40000      // N * 32 f32 = 2 MB
// ---- mask-path offsets ----
#define WS_THR    0x240000     // 4 * N f32 = 256 KB
#define WS_AGG_M  0x280000     // [N][64] f32 = 4 MB
#define WS_WT_M   0x680000     // [192][128] f32 = 96 KB (ends 0x698000)
#define WS_T2     0x6A0000     // N f32 = 64 KB (fits gap before mask)
#define WS_MASK   0x700000     // 128 chunks * N * 4 words u32 = 32 MB
#define WS_NEED_M 0x2700000    // 40.9 MB
// ---- fallback offsets (round-2 layout) ----
#define WS_CJ_F   0x400000
#define WS_AGG_F  0xC00000
#define WS_WT_F   0x1000000
#define JS   16
#define TJF  (NPTS/JS)

__device__ __forceinline__ float d2f(const float4 a, const float4 b) {
  v2f d0 = {a.x - b.x, a.y - b.y};
  v2f d1 = {a.z - b.z, a.w - b.w};
  v2f pr = d0*d0 + d1*d1;
  return pr.x + pr.y;
}

// ---------------- Kernel 1: s (fp64 accumulate) and h projections ----------------
__global__ __launch_bounds__(256) void k1_proj(
    const float* __restrict__ x, const float* __restrict__ Ws, const float* __restrict__ bs,
    const float* __restrict__ Wh, const float* __restrict__ bh,
    float4* __restrict__ s4, float* __restrict__ h) {
  __shared__ float lws[SD*CIN];
  __shared__ float lwh[PD*CIN];
  __shared__ float lbs[SD];
  __shared__ float lbh[PD];
  __shared__ float lx[256*36];
  const int t = threadIdx.x;
  for (int i2 = t; i2 < SD*CIN; i2 += 256) lws[i2] = Ws[i2];
  for (int i2 = t; i2 < PD*CIN; i2 += 256) lwh[i2] = Wh[i2];
  if (t < SD) lbs[t] = bs[t];
  if (t < PD) lbh[t] = bh[t];
  const int row0 = blockIdx.x * 256;
  double sacc[SD] = {0.0, 0.0, 0.0, 0.0};
  float  hacc[PD];
#pragma unroll
  for (int p = 0; p < PD; ++p) hacc[p] = 0.f;
  for (int kc = 0; kc < 4; ++kc) {
    __syncthreads();
#pragma unroll
    for (int q = 0; q < 8; ++q) {
      int fi = q*256 + t;
      int r  = fi >> 3, kq = fi & 7;
      float4 v = *(const float4*)&x[(size_t)(row0 + r)*CIN + kc*32 + kq*4];
      *(float4*)&lx[r*36 + kq*4] = v;
    }
    __syncthreads();
#pragma unroll
    for (int k4 = 0; k4 < 8; ++k4) {
      float4 xv = *(const float4*)&lx[t*36 + k4*4];
      int kg = kc*32 + k4*4;
#pragma unroll
      for (int p = 0; p < SD; ++p) {
        float4 wv = *(const float4*)&lws[p*CIN + kg];
        sacc[p] = fma((double)xv.x, (double)wv.x, sacc[p]);
        sacc[p] = fma((double)xv.y, (double)wv.y, sacc[p]);
        sacc[p] = fma((double)xv.z, (double)wv.z, sacc[p]);
        sacc[p] = fma((double)xv.w, (double)wv.w, sacc[p]);
      }
#pragma unroll
      for (int p = 0; p < PD; ++p) {
        float4 wv = *(const float4*)&lwh[p*CIN + kg];
        hacc[p] = fmaf(xv.x, wv.x, fmaf(xv.y, wv.y, fmaf(xv.z, wv.z, fmaf(xv.w, wv.w, hacc[p]))));
      }
    }
  }
  const int i = row0 + t;
  float s0 = (float)(sacc[0] + (double)lbs[0]);
  float s1 = (float)(sacc[1] + (double)lbs[1]);
  float s2 = (float)(sacc[2] + (double)lbs[2]);
  float s3 = (float)(sacc[3] + (double)lbs[3]);
  s4[i] = make_float4(s0, s1, s2, s3);
#pragma unroll
  for (int p = 0; p < PD; ++p) h[(size_t)i*PD + p] = hacc[p] + lbh[p];
}

// ---------------- Kernel 2a: per-query sample threshold t1 ----------------
__global__ __launch_bounds__(256) void k2a_thresh(
    const float4* __restrict__ s4, float* __restrict__ thrq) {
  __shared__ float4 tile[256];
  const int t = threadIdx.x, b = blockIdx.x;
  const int qg = b >> 2, r = b & 3;
  const int q = qg*256 + t;
  const int jbase = r*4096 + (qg & 15)*256;
  tile[t] = s4[jbase + t];
  const float4 sq = s4[q];
  __syncthreads();
  float val[KNN];
#pragma unroll
  for (int u = 0; u < KNN; ++u) val[u] = d2f(sq, tile[u]);
  float cmax = val[0]; int cpos = 0;
#pragma unroll
  for (int u = 1; u < KNN; ++u) { if (val[u] > cmax) { cmax = val[u]; cpos = u; } }
  for (int j = KNN; j < 256; ++j) {
    float e = d2f(sq, tile[j]);
    if (e < cmax) {
#pragma unroll
      for (int u = 0; u < KNN; ++u) if (u == cpos) val[u] = e;
      cmax = val[0]; cpos = 0;
#pragma unroll
      for (int u = 1; u < KNN; ++u) { if (val[u] > cmax) { cmax = val[u]; cpos = u; } }
    }
  }
  thrq[r*NPTS + q] = cmax;
}

// ---------------- Kernel 2c: refine threshold via 12-level counts over j in [0,2048) ------------
// 8 thr/query (j-slices of 256), 2 queries/thread. t2 = deepest level with count >= 16
// (count>=16 => t2 >= 16th-of-subset >= 16th-of-full: exact superset guarantee).
__global__ __launch_bounds__(256) void k2c_refine(
    const float4* __restrict__ s4, const float* __restrict__ thrq, float* __restrict__ t2) {
  __shared__ float4 tile[2048];   // 32 KB
  const int t = threadIdx.x;
#pragma unroll
  for (int g = 0; g < 8; ++g) tile[g*256 + t] = s4[g*256 + t];
  const int tq = t & 7;           // j-slice
  const int qp = t >> 3;          // 0..31
  const int q0 = blockIdx.x*64 + qp*2;
  const int q1 = q0 + 1;
  const float4 sa = s4[q0], sb = s4[q1];
  float t1a = fminf(fminf(thrq[q0], thrq[NPTS+q0]), fminf(thrq[2*NPTS+q0], thrq[3*NPTS+q0]));
  float t1b = fminf(fminf(thrq[q1], thrq[NPTS+q1]), fminf(thrq[2*NPTS+q1], thrq[3*NPTS+q1]));
  __syncthreads();
  const float FACT = 0.81225239635623547f;   // 2^-0.3 (rank ratio ~1.52)
  float tga[RL], tgb[RL];
  tga[0] = t1a; tgb[0] = t1b;
#pragma unroll
  for (int g = 1; g < RL; ++g) { tga[g] = tga[g-1]*FACT; tgb[g] = tgb[g-1]*FACT; }
  int ca[RL], cb[RL];
#pragma unroll
  for (int g = 0; g < RL; ++g) { ca[g] = 0; cb[g] = 0; }
  for (int u = 0; u < 256; ++u) {
    float4 p = tile[tq*256 + u];
    float ea = d2f(sa, p), eb = d2f(sb, p);
#pragma unroll
    for (int g = 0; g < RL; ++g) {
      ca[g] += (ea <= tga[g]) ? 1 : 0;
      cb[g] += (eb <= tgb[g]) ? 1 : 0;
    }
  }
#pragma unroll
  for (int g = 0; g < RL; ++g) {
#pragma unroll
    for (int d = 4; d >= 1; d >>= 1) {
      ca[g] += __shfl_down(ca[g], d, 8);
      cb[g] += __shfl_down(cb[g], d, 8);
    }
  }
  if (tq == 0) {
    float va = t1a, vb = t1b;
#pragma unroll
    for (int g = 1; g < RL; ++g) {
      if (ca[g] >= KNN) va = tga[g];
      if (cb[g] >= KNN) vb = tgb[g];
    }
    t2[q0] = va;
    t2[q1] = vb;
  }
}

// ---------------- Kernel 2b: full scan -> bitmask (threshold t2) ----------------
// mask layout chunk-major: word[(c*16384 + q)*4 + w], bit b of word w <-> j = c*128 + w*32 + b.
__global__ __launch_bounds__(256) void k2b_mask(
    const float4* __restrict__ s4, const float* __restrict__ t2, uint* __restrict__ maskw) {
  __shared__ float4 tile[128];
  const int t  = threadIdx.x;
  const int c  = blockIdx.x >> 3;   // 128 chunks
  const int ig = blockIdx.x & 7;    // 8 query groups of 2048
  if (t < 128) tile[t] = s4[c*128 + t];
  const int q0 = ig*2048 + t;
  float4 sq[8]; float thr[8];
#pragma unroll
  for (int m = 0; m < 8; ++m) {
    int q = q0 + m*256;
    sq[m] = s4[q];
    thr[m] = t2[q];
  }
  __syncthreads();
#pragma unroll 1
  for (int w = 0; w < 4; ++w) {
    uint msk[8];
#pragma unroll
    for (int m = 0; m < 8; ++m) msk[m] = 0u;
#pragma unroll
    for (int bit = 31; bit >= 0; --bit) {
      float4 p = tile[w*32 + bit];
#pragma unroll
      for (int m = 0; m < 8; ++m) {
        msk[m] = msk[m] + msk[m] + (d2f(sq[m], p) <= thr[m] ? 1u : 0u);
      }
    }
#pragma unroll
    for (int m = 0; m < 8; ++m) {
      int q = q0 + m*256;
      maskw[((size_t)c*NPTS + q)*4 + w] = msk[m];
    }
  }
}

// ---------------- Kernel 3: phased recovery + tournament + fused aggregation ----------------
// block = 256 thr = 16 queries x 16 threads. Thread tq covers chunks [tq*8, tq*8+8).
__global__ __launch_bounds__(256) void k3_sel(
    const float4* __restrict__ s4, const float* __restrict__ h,
    const uint4* __restrict__ maskw, float* __restrict__ agg) {
  __shared__ unsigned short cand[256*CSTR];   // 25 KB
  const int t  = threadIdx.x;
  const int ql = t >> 4, tq = t & 15;
  const int q  = blockIdx.x*16 + ql;
  const float4 sq = s4[q];
  int cnt = 0;
  // ---- phase A: extract set-bit j's to LDS (no loads inside the while body) ----
#pragma unroll
  for (int b2 = 0; b2 < 2; ++b2) {
    uint4 mw[4];
#pragma unroll
    for (int u = 0; u < 4; ++u) {
      int c = tq*8 + b2*4 + u;
      mw[u] = maskw[(size_t)c*NPTS + q];
    }
#pragma unroll
    for (int u = 0; u < 4; ++u) {
      int c = tq*8 + b2*4 + u;
      uint wv[4] = {mw[u].x, mw[u].y, mw[u].z, mw[u].w};
#pragma unroll
      for (int w = 0; w < 4; ++w) {
        uint bits = wv[w];
        while (bits) {
          int b = __builtin_ctz(bits); bits &= bits - 1;
          if (cnt < CCAP) cand[t*CSTR + cnt] = (unsigned short)(c*128 + w*32 + b);
          ++cnt;
        }
      }
    }
  }
  cnt = cnt < CCAP ? cnt : CCAP;
  // ---- phase B: batched gathers + register top-16 (ascending j order kept) ----
  float val[KNN]; int vid[KNN];
#pragma unroll
  for (int u = 0; u < KNN; ++u) { val[u] = FLTMAX; vid[u] = 0x3FFFFFFF; }
  float cmax = FLTMAX; int cpos = 0;
  for (int u0 = 0; u0 < CCAP; u0 += 4) {
    int jj[4]; float4 pj[4];
#pragma unroll
    for (int v = 0; v < 4; ++v) {
      int uu = u0 + v;
      jj[v] = (uu < cnt) ? (int)cand[t*CSTR + uu] : -1;
      pj[v] = s4[jj[v] < 0 ? 0 : jj[v]];
    }
#pragma unroll
    for (int v = 0; v < 4; ++v) {
      float e = (jj[v] >= 0) ? d2f(sq, pj[v]) : FLTMAX;
      if (e < cmax) {
#pragma unroll
        for (int u = 0; u < KNN; ++u) if (u == cpos) { val[u] = e; vid[u] = jj[v]; }
        cmax = val[0]; cpos = 0;
#pragma unroll
        for (int u = 1; u < KNN; ++u) { if (val[u] > cmax) { cmax = val[u]; cpos = u; } }
      }
    }
  }
  // ---- phase C: 16-round tournament over the query's 16 lanes, fused aggregation ----
  // exact (d2, j) lexicographic order == reference top_k tie semantics (stable, low j first)
  float msum0 = 0.f, msum1 = 0.f, mmax0 = -FLTMAX, mmax1 = -FLTMAX;
#pragma unroll 1
  for (int r = 0; r < KNN; ++r) {
    float bd = val[0]; int bj = vid[0];
#pragma unroll
    for (int u = 1; u < KNN; ++u) {
      bool lt = (val[u] < bd) || (val[u] == bd && vid[u] < bj);
      bd = lt ? val[u] : bd; bj = lt ? vid[u] : bj;
    }
    float rd = bd; int rj = bj;
#pragma unroll
    for (int m = 1; m < 16; m <<= 1) {
      float od = __shfl_xor(rd, m, 64);
      int   oj = __shfl_xor(rj, m, 64);
      bool lt = (od < rd) || (od == rd && oj < rj);
      rd = lt ? od : rd; rj = lt ? oj : rj;
    }
    bool mine = (bd == rd) && (bj == rj);
#pragma unroll
    for (int u = 0; u < KNN; ++u) {
      bool kill = mine && (val[u] == rd) && (vid[u] == rj);
      val[u] = kill ? FLTMAX : val[u];
      vid[u] = kill ? 0x3FFFFFFF : vid[u];
    }
    float w = __expf(-10.f * rd);
    float2 hv = *(const float2*)&h[(size_t)rj*PD + tq*2];
    float m0 = hv.x*w, m1 = hv.y*w;
    msum0 += m0; msum1 += m1;
    mmax0 = fmaxf(mmax0, m0); mmax1 = fmaxf(mmax1, m1);
  }
  *(float2*)&agg[(size_t)q*64 + tq*2]      = make_float2(msum0*0.0625f, msum1*0.0625f);
  *(float2*)&agg[(size_t)q*64 + 32 + tq*2] = make_float2(mmax0, mmax1);
}

// ================= Fallback path (round-2, proven) =================
__global__ __launch_bounds__(256) void k2_knn_fb(
    const float4* __restrict__ s4, unsigned short* __restrict__ cand_j) {
  __shared__ float4 tile[TJF];
  __shared__ int    lbuf[256*33];
  const int t  = threadIdx.x;
  const int ib = blockIdx.x & 31;
  const int jc = blockIdx.x >> 5;
  const int jbase = jc * TJF;
#pragma unroll
  for (int g = 0; g < 4; ++g) tile[g*256 + t] = s4[jbase + g*256 + t];
  const int ia = ib*256 + t;
  const int ic = ia + 8192;
  const float4 sa = s4[ia];
  const float4 sc = s4[ic];
  __syncthreads();
  float va[KNN], vb[KNN]; int ja[KNN], jb[KNN];
#pragma unroll
  for (int q = 0; q < KNN; ++q) { va[q] = FLTMAX; ja[q] = 0; vb[q] = FLTMAX; jb[q] = 0; }
  float cma = FLTMAX, cmb = FLTMAX;
  int cpa = 0, cpb = 0, ca = 0, cb = 0;
  auto insertA = [&](float e, int jj) {
#pragma unroll
    for (int q = 0; q < KNN; ++q) if (q == cpa) { va[q] = e; ja[q] = jj; }
    cma = va[0]; cpa = 0;
#pragma unroll
    for (int q = 1; q < KNN; ++q) { if (va[q] > cma) { cma = va[q]; cpa = q; } }
  };
  auto insertB = [&](float e, int jj) {
#pragma unroll
    for (int q = 0; q < KNN; ++q) if (q == cpb) { vb[q] = e; jb[q] = jj; }
    cmb = vb[0]; cpb = 0;
#pragma unroll
    for (int q = 1; q < KNN; ++q) { if (vb[q] > cmb) { cmb = vb[q]; cpb = q; } }
  };
  auto compactA = [&]() {
    for (int u = 0; u < ca; ++u) {
      int jj = lbuf[t*33 + u];
      float e = d2f(sa, tile[jj]);
      if (e < cma) insertA(e, jj);
    }
    ca = 0;
  };
  auto compactB = [&]() {
    for (int u = 0; u < cb; ++u) {
      int jj = lbuf[t*33 + 16 + u];
      float e = d2f(sc, tile[jj]);
      if (e < cmb) insertB(e, jj);
    }
    cb = 0;
  };
  for (int ob = 0; ob < TJF/8; ++ob) {
#pragma unroll
    for (int u = 0; u < 8; ++u) {
      int jj = ob*8 + u;
      float4 p = tile[jj];
      float ea = d2f(sa, p);
      float eb = d2f(sc, p);
      if (ea < cma) { lbuf[t*33 + ca] = jj; ++ca; }
      if (eb < cmb) { lbuf[t*33 + 16 + cb] = jj; ++cb; }
    }
    if (__any(ca > 8)) compactA();
    if (__any(cb > 8)) compactB();
  }
  compactA(); compactB();
#pragma unroll
  for (int q = 0; q < KNN; ++q) {
    int c = jc*KNN + q;
    cand_j[(size_t)c*NPTS + ia] = (unsigned short)(ja[q] + jbase);
    cand_j[(size_t)c*NPTS + ic] = (unsigned short)(jb[q] + jbase);
  }
}

__global__ __launch_bounds__(256) void k3_merge_fb(
    const float4* __restrict__ s4, const float4* __restrict__ h4,
    const unsigned short* __restrict__ cand_j, float* __restrict__ agg) {
  __shared__ float le[64*67];
  __shared__ int   lj[64*67];
  const int t  = threadIdx.x;
  const int il = t & 63, tq = t >> 6;
  const int i  = blockIdx.x*64 + il;
  const float4 si = s4[i];
  float val[KNN]; int vid[KNN];
#pragma unroll
  for (int q = 0; q < KNN; ++q) { val[q] = FLTMAX; vid[q] = 0; }
  float cmax = FLTMAX; int cpos = 0;
  for (int u = 0; u < 64; ++u) {
    int c = tq*64 + u;
    int j = cand_j[(size_t)c*NPTS + i];
    float e = d2f(si, s4[j]);
    if (e < cmax) {
#pragma unroll
      for (int q = 0; q < KNN; ++q) if (q == cpos) { val[q] = e; vid[q] = j; }
      cmax = val[0]; cpos = 0;
#pragma unroll
      for (int q = 1; q < KNN; ++q) { if (val[q] > cmax) { cmax = val[q]; cpos = q; } }
    }
  }
#pragma unroll
  for (int q = 0; q < KNN; ++q) {
    le[il*67 + tq*16 + q] = val[q];
    lj[il*67 + tq*16 + q] = vid[q];
  }
  __syncthreads();
  if (t < 64) {
    float mv[KNN]; int mj[KNN];
#pragma unroll
    for (int q = 0; q < KNN; ++q) { mv[q] = FLTMAX; mj[q] = 0; }
    float cm2 = FLTMAX; int cp2 = 0;
    for (int u = 0; u < 64; ++u) {
      float e = le[t*67 + u];
      int   j = lj[t*67 + u];
      if (e < cm2) {
#pragma unroll
        for (int q = 0; q < KNN; ++q) if (q == cp2) { mv[q] = e; mj[q] = j; }
        cm2 = mv[0]; cp2 = 0;
#pragma unroll
        for (int q = 1; q < KNN; ++q) { if (mv[q] > cm2) { cm2 = mv[q]; cp2 = q; } }
      }
    }
#pragma unroll
    for (int q = 0; q < KNN; ++q) {
      le[t*67 + q] = __expf(-10.f * mv[q]);
      lj[t*67 + q] = mj[q];
    }
  }
  __syncthreads();
  float ms[8], mm[8];
#pragma unroll
  for (int p = 0; p < 8; ++p) { ms[p] = 0.f; mm[p] = -FLTMAX; }
#pragma unroll 1
  for (int q = 0; q < KNN; ++q) {
    float w = le[il*67 + q];
    int   j = lj[il*67 + q];
    float4 a = h4[(size_t)j*8 + tq*2];
    float4 b = h4[(size_t)j*8 + tq*2 + 1];
    float m0 = a.x*w, m1 = a.y*w, m2 = a.z*w, m3 = a.w*w;
    float m4 = b.x*w, m5 = b.y*w, m6 = b.z*w, m7 = b.w*w;
    ms[0] += m0; mm[0] = fmaxf(mm[0], m0);
    ms[1] += m1; mm[1] = fmaxf(mm[1], m1);
    ms[2] += m2; mm[2] = fmaxf(mm[2], m2);
    ms[3] += m3; mm[3] = fmaxf(mm[3], m3);
    ms[4] += m4; mm[4] = fmaxf(mm[4], m4);
    ms[5] += m5; mm[5] = fmaxf(mm[5], m5);
    ms[6] += m6; mm[6] = fmaxf(mm[6], m6);
    ms[7] += m7; mm[7] = fmaxf(mm[7], m7);
  }
  float4 o0 = make_float4(ms[0]*0.0625f, ms[1]*0.0625f, ms[2]*0.0625f, ms[3]*0.0625f);
  float4 o1 = make_float4(ms[4]*0.0625f, ms[5]*0.0625f, ms[6]*0.0625f, ms[7]*0.0625f);
  *(float4*)&agg[(size_t)i*64 + tq*8]      = o0;
  *(float4*)&agg[(size_t)i*64 + tq*8 + 4]  = o1;
  *(float4*)&agg[(size_t)i*64 + 32 + tq*8]     = make_float4(mm[0], mm[1], mm[2], mm[3]);
  *(float4*)&agg[(size_t)i*64 + 32 + tq*8 + 4] = make_float4(mm[4], mm[5], mm[6], mm[7]);
}

// ---------------- Kernel 4a: pack/transpose weights ----------------
__global__ __launch_bounds__(256) void k4a_wt(
    const float* __restrict__ W1, const float* __restrict__ W2, float* __restrict__ wT) {
  int idx = blockIdx.x*256 + threadIdx.x;
  if (idx >= 192*COUT) return;
  int k = idx >> 7, c = idx & 127;
  float v = (k < 128) ? W1[(size_t)c*128 + k] : W2[(size_t)c*64 + (k - 128)];
  wT[(size_t)k*COUT + c] = v;
}

// ---------------- Kernel 4 v2: out = x@W1^T + agg@W2^T + b2 (64x128 tile, 8x4/thread) ------
__global__ __launch_bounds__(256) void k4_out2(
    const float* __restrict__ x, const float* __restrict__ agg,
    const float* __restrict__ wT, const float* __restrict__ b2,
    float* __restrict__ out) {
  __shared__ float xa[64*192];   // 48 KB
  const int t = threadIdx.x;
  const int row0 = blockIdx.x * 64;
#pragma unroll
  for (int g = 0; g < 8; ++g) {
    int idx = g*256 + t;                 // 64 rows x 32 float4 of x
    int r = idx >> 5, k4 = idx & 31;
    *(float4*)&xa[r*192 + k4*4] = *(const float4*)&x[(size_t)(row0+r)*CIN + k4*4];
  }
#pragma unroll
  for (int g = 0; g < 4; ++g) {
    int idx = g*256 + t;                 // 64 rows x 16 float4 of agg
    int r = idx >> 4, k4 = idx & 15;
    *(float4*)&xa[r*192 + 128 + k4*4] = *(const float4*)&agg[(size_t)(row0+r)*64 + k4*4];
  }
  __syncthreads();
  const int c4 = t & 31;
  const int r8 = t >> 5;
  float acc[8][4];
#pragma unroll
  for (int r = 0; r < 8; ++r) { acc[r][0]=0.f; acc[r][1]=0.f; acc[r][2]=0.f; acc[r][3]=0.f; }
  for (int k = 0; k < 192; k += 4) {
    float4 w0 = *(const float4*)&wT[(size_t)(k+0)*COUT + c4*4];
    float4 w1 = *(const float4*)&wT[(size_t)(k+1)*COUT + c4*4];
    float4 w2 = *(const float4*)&wT[(size_t)(k+2)*COUT + c4*4];
    float4 w3 = *(const float4*)&wT[(size_t)(k+3)*COUT + c4*4];
#pragma unroll
    for (int r = 0; r < 8; ++r) {
      float4 xv = *(const float4*)&xa[(r8*8 + r)*192 + k];
      acc[r][0] = fmaf(xv.x, w0.x, fmaf(xv.y, w1.x, fmaf(xv.z, w2.x, fmaf(xv.w, w3.x, acc[r][0]))));
      acc[r][1] = fmaf(xv.x, w0.y, fmaf(xv.y, w1.y, fmaf(xv.z, w2.y, fmaf(xv.w, w3.y, acc[r][1]))));
      acc[r][2] = fmaf(xv.x, w0.z, fmaf(xv.y, w1.z, fmaf(xv.z, w2.z, fmaf(xv.w, w3.z, acc[r][2]))));
      acc[r][3] = fmaf(xv.x, w0.w, fmaf(xv.y, w1.w, fmaf(xv.z, w2.w, fmaf(xv.w, w3.w, acc[r][3]))));
    }
  }
  float4 bias = *(const float4*)&b2[c4*4];
#pragma unroll
  for (int r = 0; r < 8; ++r) {
    float4 o = make_float4(acc[r][0]+bias.x, acc[r][1]+bias.y, acc[r][2]+bias.z, acc[r][3]+bias.w);
    *(float4*)&out[(size_t)(row0 + r8*8 + r)*COUT + c4*4] = o;
  }
}

extern "C" void kernel_launch(void* const* d_in, const int* in_sizes, int n_in,
                              void* d_out, int out_size, void* d_ws, size_t ws_size,
                              hipStream_t stream) {
  const float* x  = (const float*)d_in[0];
  const float* Ws = (const float*)d_in[1];
  const float* bs = (const float*)d_in[2];
  const float* Wh = (const float*)d_in[3];
  const float* bh = (const float*)d_in[4];
  const float* W1 = (const float*)d_in[5];
  const float* W2 = (const float*)d_in[6];
  const float* b2 = (const float*)d_in[7];
  float* out = (float*)d_out;

  char* ws = (char*)d_ws;
  float4* s4 = (float4*)(ws + WS_S4);
  float*  h  = (float*) (ws + WS_H);

  k1_proj<<<NPTS/256, 256, 0, stream>>>(x, Ws, bs, Wh, bh, s4, h);

  if (ws_size >= (size_t)WS_NEED_M) {
    float* thrq = (float*)(ws + WS_THR);
    float* t2   = (float*)(ws + WS_T2);
    float* agg  = (float*)(ws + WS_AGG_M);
    float* wT   = (float*)(ws + WS_WT_M);
    uint*  mw   = (uint*) (ws + WS_MASK);
    k2a_thresh<<<256, 256, 0, stream>>>(s4, thrq);
    k2c_refine<<<NPTS/64, 256, 0, stream>>>(s4, thrq, t2);
    k2b_mask<<<1024, 256, 0, stream>>>(s4, t2, mw);
    k3_sel<<<NPTS/16, 256, 0, stream>>>(s4, h, (const uint4*)mw, agg);
    k4a_wt<<<(192*COUT + 255)/256, 256, 0, stream>>>(W1, W2, wT);
    k4_out2<<<NPTS/64, 256, 0, stream>>>(x, agg, wT, b2, out);
  } else {
    unsigned short* cj = (unsigned short*)(ws + WS_CJ_F);
    float* agg = (float*)(ws + WS_AGG_F);
    float* wT  = (float*)(ws + WS_WT_F);
    k2_knn_fb<<<512, 256, 0, stream>>>(s4, cj);
    k3_merge_fb<<<NPTS/64, 256, 0, stream>>>(s4, (const float4*)h, cj, agg);
    k4a_wt<<<(192*COUT + 255)/256, 256, 0, stream>>>(W1, W2, wT);
    k4_out2<<<NPTS/64, 256, 0, stream>>>(x, agg, wT, b2, out);
  }
}

// Round 5
// 253.244 us; speedup vs baseline: 2.2421x; 1.6329x over previous
//
#include <hip/hip_runtime.h>
#include <hip/hip_bf16.h>

// GravNetConv: N=16384, C_IN=128, S=4, P=32, K=16, C_OUT=128.
// Mask path: [k1] proj (64-row x 4-quarter waves, fp64 s) -> [k2t] per-query threshold
// via radix-ladder histogram (integer-exact, no top-k maintenance) -> [k2b] full N^2
// scan -> bitmask -> [k3_sel] phased recovery + 16-lane tournament + fused aggregation
// -> [k4a/k4_out2] out = x@W1^T + agg@W2^T + b2.
// Fallback path (ws_size < 41MB): round-2 kernels.

#define NPTS 16384
#define CIN  128
#define SD   4
#define PD   32
#define KNN  16
#define COUT 128
#define FLTMAX 3.4028234663852886e+38f
#define CCAP 48        // k3 per-thread candidate cap (16 thr/query)
#define CSTR 50        // LDS stride for cand (u16)
#define NBIN 33        // k2t bins 0..32 (quarter-octave-ish ladder via top-2 mantissa bits)

typedef float v2f __attribute__((ext_vector_type(2)));
typedef unsigned int uint;

// ---- shared offsets (both paths) ----
#define WS_S4     0            // N * float4 = 256 KB
#define WS_H      0x40000      // N * 32 f32 = 2 MB
// ---- mask-path offsets ----
#define WS_AGG_M  0x280000     // [N][64] f32 = 4 MB
#define WS_WT_M   0x680000     // [192][128] f32 = 96 KB
#define WS_T2     0x6A0000     // N f32 = 64 KB
#define WS_MASK   0x700000     // 128 chunks * N * 4 words u32 = 32 MB
#define WS_NEED_M 0x2700000    // 40.9 MB
// ---- fallback offsets ----
#define WS_CJ_F   0x400000
#define WS_AGG_F  0xC00000
#define WS_WT_F   0x1000000
#define JS   16
#define TJF  (NPTS/JS)

__device__ __forceinline__ float d2f(const float4 a, const float4 b) {
  v2f d0 = {a.x - b.x, a.y - b.y};
  v2f d1 = {a.z - b.z, a.w - b.w};
  v2f pr = d0*d0 + d1*d1;
  return pr.x + pr.y;
}

// ---------------- Kernel 1: s (fp64 accumulate) and h projections ----------------
// 64 rows/block, 4 k-quarter waves; partials reduced via LDS in fixed order.
__global__ __launch_bounds__(256) void k1_proj(
    const float* __restrict__ x, const float* __restrict__ Ws, const float* __restrict__ bs,
    const float* __restrict__ Wh, const float* __restrict__ bh,
    float4* __restrict__ s4, float* __restrict__ h) {
  __shared__ float  lw[36*128];     // rows 0-3 = Ws, 4-35 = Wh (18 KB)
  __shared__ float  lx[64*132];     // 33.8 KB
  __shared__ double rs[3*64*5];     // fp64 partials, stride 5 (7.7 KB)
  __shared__ float  rh[3*64*33];    // fp32 partials, stride 33 (25.3 KB)
  const int t = threadIdx.x;
  const int row0 = blockIdx.x * 64;
  for (int i2 = t; i2 < 36*128; i2 += 256)
    lw[i2] = (i2 < 512) ? Ws[i2] : Wh[i2 - 512];
#pragma unroll
  for (int g = 0; g < 8; ++g) {
    int fi = g*256 + t;
    int r = fi >> 5, c4 = fi & 31;
    *(float4*)&lx[r*132 + c4*4] = *(const float4*)&x[(size_t)(row0 + r)*CIN + c4*4];
  }
  __syncthreads();
  const int kq = t >> 6;          // wave = k-quarter
  const int r  = t & 63;
  const int kb = kq * 32;
  double sacc[4] = {0.0, 0.0, 0.0, 0.0};
  float  hacc[32];
#pragma unroll
  for (int p = 0; p < 32; ++p) hacc[p] = 0.f;
#pragma unroll
  for (int k4 = 0; k4 < 8; ++k4) {
    float4 xv = *(const float4*)&lx[r*132 + kb + k4*4];
    int kg = kb + k4*4;
#pragma unroll
    for (int p = 0; p < 4; ++p) {
      float4 wv = *(const float4*)&lw[p*128 + kg];      // wave-uniform: broadcast
      sacc[p] = fma((double)xv.x, (double)wv.x, sacc[p]);
      sacc[p] = fma((double)xv.y, (double)wv.y, sacc[p]);
      sacc[p] = fma((double)xv.z, (double)wv.z, sacc[p]);
      sacc[p] = fma((double)xv.w, (double)wv.w, sacc[p]);
    }
#pragma unroll
    for (int p = 0; p < 32; ++p) {
      float4 wv = *(const float4*)&lw[(4+p)*128 + kg];  // broadcast
      hacc[p] = fmaf(xv.x, wv.x, fmaf(xv.y, wv.y, fmaf(xv.z, wv.z, fmaf(xv.w, wv.w, hacc[p]))));
    }
  }
  if (kq > 0) {
    const int bq = kq - 1;
#pragma unroll
    for (int d = 0; d < 4; ++d) rs[(bq*64 + r)*5 + d] = sacc[d];
#pragma unroll
    for (int p = 0; p < 32; ++p) rh[(bq*64 + r)*33 + p] = hacc[p];
  }
  __syncthreads();
  if (kq == 0) {
    const int row = row0 + r;
    float so[4];
#pragma unroll
    for (int d = 0; d < 4; ++d) {
      double sd = sacc[d] + rs[(0*64 + r)*5 + d] + rs[(1*64 + r)*5 + d]
                + rs[(2*64 + r)*5 + d] + (double)bs[d];
      so[d] = (float)sd;
    }
    s4[row] = make_float4(so[0], so[1], so[2], so[3]);
#pragma unroll
    for (int p4 = 0; p4 < 8; ++p4) {
      float o[4];
#pragma unroll
      for (int c = 0; c < 4; ++c) {
        int p = p4*4 + c;
        o[c] = hacc[p] + rh[(0*64 + r)*33 + p] + rh[(1*64 + r)*33 + p]
             + rh[(2*64 + r)*33 + p] + bh[p];
      }
      *(float4*)&h[(size_t)row*PD + p4*4] = make_float4(o[0], o[1], o[2], o[3]);
    }
  }
}

// ---------------- Kernel 2t: per-query threshold via radix-ladder histogram ----------------
// 16 queries/block, 16 thr/query, each scans 128 of the 2048-pt subset (j in [0,2048)).
// tau_top = max d2 to 16 anchors (j = 0,128,...,1920)  =>  count(tau_top) >= 16 guaranteed.
// key(d2) = bits(d2)>>21 (exact monotone); bin = clamp(ktop-key, 0, 32); private LDS hist;
// suffix-scan picks deepest bin g with cum >= 16; t2 = largest float with key == ktop-g.
__global__ __launch_bounds__(256) void k2t_thresh(
    const float4* __restrict__ s4, float* __restrict__ t2) {
  __shared__ float4 tile[2064];       // 2048 + 16 swizzle pad (33 KB)
  __shared__ uint   lhist[256*NBIN];  // private per-thread hist (33.8 KB)
  const int t = threadIdx.x;
#pragma unroll
  for (int g = 0; g < 8; ++g) {
    int j = g*256 + t;
    tile[j + (j >> 7)] = s4[j];       // phys = j + j/128: breaks 2KB stride conflicts
  }
#pragma unroll
  for (int b = 0; b < NBIN; ++b) lhist[t*NBIN + b] = 0u;
  const int ql = t >> 4, tq = t & 15;
  const int q  = blockIdx.x*16 + ql;
  const float4 sq = s4[q];
  __syncthreads();
  // tau_top over 16 anchors (anchor for lane tq at phys tq*129)
  float tau = d2f(sq, tile[tq*129]);
#pragma unroll
  for (int m = 1; m < 16; m <<= 1) tau = fmaxf(tau, __shfl_xor(tau, m, 16));
  const int ktop = (int)(__float_as_uint(tau) >> 21);
  const int hb = t*NBIN;
#pragma unroll 4
  for (int u = 0; u < 128; ++u) {
    float4 p = tile[tq*129 + u];      // phys of j = tq*128+u
    float e = d2f(sq, p);
    int key = (int)(__float_as_uint(e) >> 21);
    int rel = ktop - key;
    rel = rel < 0 ? 0 : (rel > 32 ? 32 : rel);
    atomicAdd(&lhist[hb + rel], 1u);  // private slot: ds_add, no contention
  }
  __syncthreads();
  // reduce 16 private hists per query; lane tq owns bins {2tq, 2tq+1}
  uint c0 = 0, c1 = 0;
  const int qb = ql*16;
  for (int u = 0; u < 16; ++u) {
    c0 += lhist[(qb + u)*NBIN + tq*2];
    c1 += (tq*2 + 1 < NBIN) ? lhist[(qb + u)*NBIN + tq*2 + 1] : 0u;
  }
  int S = (int)(c0 + c1);
#pragma unroll
  for (int d = 1; d < 16; d <<= 1) {
    int v = __shfl_down(S, d, 16);
    S += (tq + d < 16) ? v : 0;       // S = sum of bins >= 2tq
  }
  int g = -1;
  if (S >= KNN) g = 2*tq;
  if (S - (int)c0 >= KNN) g = 2*tq + 1;
#pragma unroll
  for (int m = 1; m < 16; m <<= 1) g = max(g, __shfl_xor(g, m, 16));
  if (tq == 0) {
    uint K = (uint)(ktop - g);
    t2[q] = __uint_as_float((K << 21) | 0x1FFFFFu);
  }
}

// ---------------- Kernel 2b: full scan -> bitmask (threshold t2) ----------------
__global__ __launch_bounds__(256) void k2b_mask(
    const float4* __restrict__ s4, const float* __restrict__ t2, uint* __restrict__ maskw) {
  __shared__ float4 tile[128];
  const int t  = threadIdx.x;
  const int c  = blockIdx.x >> 3;   // 128 chunks
  const int ig = blockIdx.x & 7;    // 8 query groups of 2048
  if (t < 128) tile[t] = s4[c*128 + t];
  const int q0 = ig*2048 + t;
  float4 sq[8]; float thr[8];
#pragma unroll
  for (int m = 0; m < 8; ++m) {
    int q = q0 + m*256;
    sq[m] = s4[q];
    thr[m] = t2[q];
  }
  __syncthreads();
#pragma unroll 1
  for (int w = 0; w < 4; ++w) {
    uint msk[8];
#pragma unroll
    for (int m = 0; m < 8; ++m) msk[m] = 0u;
#pragma unroll
    for (int bit = 31; bit >= 0; --bit) {
      float4 p = tile[w*32 + bit];
#pragma unroll
      for (int m = 0; m < 8; ++m) {
        msk[m] = msk[m] + msk[m] + (d2f(sq[m], p) <= thr[m] ? 1u : 0u);
      }
    }
#pragma unroll
    for (int m = 0; m < 8; ++m) {
      int q = q0 + m*256;
      maskw[((size_t)c*NPTS + q)*4 + w] = msk[m];
    }
  }
}

// ---------------- Kernel 3: phased recovery + tournament + fused aggregation ----------------
__global__ __launch_bounds__(256) void k3_sel(
    const float4* __restrict__ s4, const float* __restrict__ h,
    const uint4* __restrict__ maskw, float* __restrict__ agg) {
  __shared__ unsigned short cand[256*CSTR];   // 25 KB
  const int t  = threadIdx.x;
  const int ql = t >> 4, tq = t & 15;
  const int q  = blockIdx.x*16 + ql;
  const float4 sq = s4[q];
  int cnt = 0;
#pragma unroll
  for (int b2 = 0; b2 < 2; ++b2) {
    uint4 mw[4];
#pragma unroll
    for (int u = 0; u < 4; ++u) {
      int c = tq*8 + b2*4 + u;
      mw[u] = maskw[(size_t)c*NPTS + q];
    }
#pragma unroll
    for (int u = 0; u < 4; ++u) {
      int c = tq*8 + b2*4 + u;
      uint wv[4] = {mw[u].x, mw[u].y, mw[u].z, mw[u].w};
#pragma unroll
      for (int w = 0; w < 4; ++w) {
        uint bits = wv[w];
        while (bits) {
          int b = __builtin_ctz(bits); bits &= bits - 1;
          if (cnt < CCAP) cand[t*CSTR + cnt] = (unsigned short)(c*128 + w*32 + b);
          ++cnt;
        }
      }
    }
  }
  cnt = cnt < CCAP ? cnt : CCAP;
  float val[KNN]; int vid[KNN];
#pragma unroll
  for (int u = 0; u < KNN; ++u) { val[u] = FLTMAX; vid[u] = 0x3FFFFFFF; }
  float cmax = FLTMAX; int cpos = 0;
  for (int u0 = 0; u0 < CCAP; u0 += 4) {
    int jj[4]; float4 pj[4];
#pragma unroll
    for (int v = 0; v < 4; ++v) {
      int uu = u0 + v;
      jj[v] = (uu < cnt) ? (int)cand[t*CSTR + uu] : -1;
      pj[v] = s4[jj[v] < 0 ? 0 : jj[v]];
    }
#pragma unroll
    for (int v = 0; v < 4; ++v) {
      float e = (jj[v] >= 0) ? d2f(sq, pj[v]) : FLTMAX;
      if (e < cmax) {
#pragma unroll
        for (int u = 0; u < KNN; ++u) if (u == cpos) { val[u] = e; vid[u] = jj[v]; }
        cmax = val[0]; cpos = 0;
#pragma unroll
        for (int u = 1; u < KNN; ++u) { if (val[u] > cmax) { cmax = val[u]; cpos = u; } }
      }
    }
  }
  float msum0 = 0.f, msum1 = 0.f, mmax0 = -FLTMAX, mmax1 = -FLTMAX;
#pragma unroll 1
  for (int r = 0; r < KNN; ++r) {
    float bd = val[0]; int bj = vid[0];
#pragma unroll
    for (int u = 1; u < KNN; ++u) {
      bool lt = (val[u] < bd) || (val[u] == bd && vid[u] < bj);
      bd = lt ? val[u] : bd; bj = lt ? vid[u] : bj;
    }
    float rd = bd; int rj = bj;
#pragma unroll
    for (int m = 1; m < 16; m <<= 1) {
      float od = __shfl_xor(rd, m, 64);
      int   oj = __shfl_xor(rj, m, 64);
      bool lt = (od < rd) || (od == rd && oj < rj);
      rd = lt ? od : rd; rj = lt ? oj : rj;
    }
    bool mine = (bd == rd) && (bj == rj);
#pragma unroll
    for (int u = 0; u < KNN; ++u) {
      bool kill = mine && (val[u] == rd) && (vid[u] == rj);
      val[u] = kill ? FLTMAX : val[u];
      vid[u] = kill ? 0x3FFFFFFF : vid[u];
    }
    float w = __expf(-10.f * rd);
    float2 hv = *(const float2*)&h[(size_t)rj*PD + tq*2];
    float m0 = hv.x*w, m1 = hv.y*w;
    msum0 += m0; msum1 += m1;
    mmax0 = fmaxf(mmax0, m0); mmax1 = fmaxf(mmax1, m1);
  }
  *(float2*)&agg[(size_t)q*64 + tq*2]      = make_float2(msum0*0.0625f, msum1*0.0625f);
  *(float2*)&agg[(size_t)q*64 + 32 + tq*2] = make_float2(mmax0, mmax1);
}

// ================= Fallback path (round-2, proven) =================
__global__ __launch_bounds__(256) void k2_knn_fb(
    const float4* __restrict__ s4, unsigned short* __restrict__ cand_j) {
  __shared__ float4 tile[TJF];
  __shared__ int    lbuf[256*33];
  const int t  = threadIdx.x;
  const int ib = blockIdx.x & 31;
  const int jc = blockIdx.x >> 5;
  const int jbase = jc * TJF;
#pragma unroll
  for (int g = 0; g < 4; ++g) tile[g*256 + t] = s4[jbase + g*256 + t];
  const int ia = ib*256 + t;
  const int ic = ia + 8192;
  const float4 sa = s4[ia];
  const float4 sc = s4[ic];
  __syncthreads();
  float va[KNN], vb[KNN]; int ja[KNN], jb[KNN];
#pragma unroll
  for (int q = 0; q < KNN; ++q) { va[q] = FLTMAX; ja[q] = 0; vb[q] = FLTMAX; jb[q] = 0; }
  float cma = FLTMAX, cmb = FLTMAX;
  int cpa = 0, cpb = 0, ca = 0, cb = 0;
  auto insertA = [&](float e, int jj) {
#pragma unroll
    for (int q = 0; q < KNN; ++q) if (q == cpa) { va[q] = e; ja[q] = jj; }
    cma = va[0]; cpa = 0;
#pragma unroll
    for (int q = 1; q < KNN; ++q) { if (va[q] > cma) { cma = va[q]; cpa = q; } }
  };
  auto insertB = [&](float e, int jj) {
#pragma unroll
    for (int q = 0; q < KNN; ++q) if (q == cpb) { vb[q] = e; jb[q] = jj; }
    cmb = vb[0]; cpb = 0;
#pragma unroll
    for (int q = 1; q < KNN; ++q) { if (vb[q] > cmb) { cmb = vb[q]; cpb = q; } }
  };
  auto compactA = [&]() {
    for (int u = 0; u < ca; ++u) {
      int jj = lbuf[t*33 + u];
      float e = d2f(sa, tile[jj]);
      if (e < cma) insertA(e, jj);
    }
    ca = 0;
  };
  auto compactB = [&]() {
    for (int u = 0; u < cb; ++u) {
      int jj = lbuf[t*33 + 16 + u];
      float e = d2f(sc, tile[jj]);
      if (e < cmb) insertB(e, jj);
    }
    cb = 0;
  };
  for (int ob = 0; ob < TJF/8; ++ob) {
#pragma unroll
    for (int u = 0; u < 8; ++u) {
      int jj = ob*8 + u;
      float4 p = tile[jj];
      float ea = d2f(sa, p);
      float eb = d2f(sc, p);
      if (ea < cma) { lbuf[t*33 + ca] = jj; ++ca; }
      if (eb < cmb) { lbuf[t*33 + 16 + cb] = jj; ++cb; }
    }
    if (__any(ca > 8)) compactA();
    if (__any(cb > 8)) compactB();
  }
  compactA(); compactB();
#pragma unroll
  for (int q = 0; q < KNN; ++q) {
    int c = jc*KNN + q;
    cand_j[(size_t)c*NPTS + ia] = (unsigned short)(ja[q] + jbase);
    cand_j[(size_t)c*NPTS + ic] = (unsigned short)(jb[q] + jbase);
  }
}

__global__ __launch_bounds__(256) void k3_merge_fb(
    const float4* __restrict__ s4, const float4* __restrict__ h4,
    const unsigned short* __restrict__ cand_j, float* __restrict__ agg) {
  __shared__ float le[64*67];
  __shared__ int   lj[64*67];
  const int t  = threadIdx.x;
  const int il = t & 63, tq = t >> 6;
  const int i  = blockIdx.x*64 + il;
  const float4 si = s4[i];
  float val[KNN]; int vid[KNN];
#pragma unroll
  for (int q = 0; q < KNN; ++q) { val[q] = FLTMAX; vid[q] = 0; }
  float cmax = FLTMAX; int cpos = 0;
  for (int u = 0; u < 64; ++u) {
    int c = tq*64 + u;
    int j = cand_j[(size_t)c*NPTS + i];
    float e = d2f(si, s4[j]);
    if (e < cmax) {
#pragma unroll
      for (int q = 0; q < KNN; ++q) if (q == cpos) { val[q] = e; vid[q] = j; }
      cmax = val[0]; cpos = 0;
#pragma unroll
      for (int q = 1; q < KNN; ++q) { if (val[q] > cmax) { cmax = val[q]; cpos = q; } }
    }
  }
#pragma unroll
  for (int q = 0; q < KNN; ++q) {
    le[il*67 + tq*16 + q] = val[q];
    lj[il*67 + tq*16 + q] = vid[q];
  }
  __syncthreads();
  if (t < 64) {
    float mv[KNN]; int mj[KNN];
#pragma unroll
    for (int q = 0; q < KNN; ++q) { mv[q] = FLTMAX; mj[q] = 0; }
    float cm2 = FLTMAX; int cp2 = 0;
    for (int u = 0; u < 64; ++u) {
      float e = le[t*67 + u];
      int   j = lj[t*67 + u];
      if (e < cm2) {
#pragma unroll
        for (int q = 0; q < KNN; ++q) if (q == cp2) { mv[q] = e; mj[q] = j; }
        cm2 = mv[0]; cp2 = 0;
#pragma unroll
        for (int q = 1; q < KNN; ++q) { if (mv[q] > cm2) { cm2 = mv[q]; cp2 = q; } }
      }
    }
#pragma unroll
    for (int q = 0; q < KNN; ++q) {
      le[t*67 + q] = __expf(-10.f * mv[q]);
      lj[t*67 + q] = mj[q];
    }
  }
  __syncthreads();
  float ms[8], mm[8];
#pragma unroll
  for (int p = 0; p < 8; ++p) { ms[p] = 0.f; mm[p] = -FLTMAX; }
#pragma unroll 1
  for (int q = 0; q < KNN; ++q) {
    float w = le[il*67 + q];
    int   j = lj[il*67 + q];
    float4 a = h4[(size_t)j*8 + tq*2];
    float4 b = h4[(size_t)j*8 + tq*2 + 1];
    float m0 = a.x*w, m1 = a.y*w, m2 = a.z*w, m3 = a.w*w;
    float m4 = b.x*w, m5 = b.y*w, m6 = b.z*w, m7 = b.w*w;
    ms[0] += m0; mm[0] = fmaxf(mm[0], m0);
    ms[1] += m1; mm[1] = fmaxf(mm[1], m1);
    ms[2] += m2; mm[2] = fmaxf(mm[2], m2);
    ms[3] += m3; mm[3] = fmaxf(mm[3], m3);
    ms[4] += m4; mm[4] = fmaxf(mm[4], m4);
    ms[5] += m5; mm[5] = fmaxf(mm[5], m5);
    ms[6] += m6; mm[6] = fmaxf(mm[6], m6);
    ms[7] += m7; mm[7] = fmaxf(mm[7], m7);
  }
  float4 o0 = make_float4(ms[0]*0.0625f, ms[1]*0.0625f, ms[2]*0.0625f, ms[3]*0.0625f);
  float4 o1 = make_float4(ms[4]*0.0625f, ms[5]*0.0625f, ms[6]*0.0625f, ms[7]*0.0625f);
  *(float4*)&agg[(size_t)i*64 + tq*8]      = o0;
  *(float4*)&agg[(size_t)i*64 + tq*8 + 4]  = o1;
  *(float4*)&agg[(size_t)i*64 + 32 + tq*8]     = make_float4(mm[0], mm[1], mm[2], mm[3]);
  *(float4*)&agg[(size_t)i*64 + 32 + tq*8 + 4] = make_float4(mm[4], mm[5], mm[6], mm[7]);
}

// ---------------- Kernel 4a: pack/transpose weights ----------------
__global__ __launch_bounds__(256) void k4a_wt(
    const float* __restrict__ W1, const float* __restrict__ W2, float* __restrict__ wT) {
  int idx = blockIdx.x*256 + threadIdx.x;
  if (idx >= 192*COUT) return;
  int k = idx >> 7, c = idx & 127;
  float v = (k < 128) ? W1[(size_t)c*128 + k] : W2[(size_t)c*64 + (k - 128)];
  wT[(size_t)k*COUT + c] = v;
}

// ---------------- Kernel 4: out = x@W1^T + agg@W2^T + b2 (32x128 tile, 4x4/thread) ----------
__global__ __launch_bounds__(256) void k4_out2(
    const float* __restrict__ x, const float* __restrict__ agg,
    const float* __restrict__ wT, const float* __restrict__ b2,
    float* __restrict__ out) {
  __shared__ float xa[32*192];   // 24.6 KB
  const int t = threadIdx.x;
  const int row0 = blockIdx.x * 32;
#pragma unroll
  for (int g = 0; g < 4; ++g) {
    int fi = g*256 + t;
    int r = fi >> 5, c4 = fi & 31;
    *(float4*)&xa[r*192 + c4*4] = *(const float4*)&x[(size_t)(row0+r)*CIN + c4*4];
  }
#pragma unroll
  for (int g = 0; g < 2; ++g) {
    int fi = g*256 + t;
    int r = fi >> 4, c4 = fi & 15;
    *(float4*)&xa[r*192 + 128 + c4*4] = *(const float4*)&agg[(size_t)(row0+r)*64 + c4*4];
  }
  __syncthreads();
  const int c4 = t & 31;
  const int rg = t >> 5;
  float acc[4][4];
#pragma unroll
  for (int r = 0; r < 4; ++r) { acc[r][0]=0.f; acc[r][1]=0.f; acc[r][2]=0.f; acc[r][3]=0.f; }
  for (int k = 0; k < 192; k += 4) {
    float4 w0 = *(const float4*)&wT[(size_t)(k+0)*COUT + c4*4];
    float4 w1 = *(const float4*)&wT[(size_t)(k+1)*COUT + c4*4];
    float4 w2 = *(const float4*)&wT[(size_t)(k+2)*COUT + c4*4];
    float4 w3 = *(const float4*)&wT[(size_t)(k+3)*COUT + c4*4];
#pragma unroll
    for (int r = 0; r < 4; ++r) {
      float4 xv = *(const float4*)&xa[(rg*4 + r)*192 + k];
      acc[r][0] = fmaf(xv.x, w0.x, fmaf(xv.y, w1.x, fmaf(xv.z, w2.x, fmaf(xv.w, w3.x, acc[r][0]))));
      acc[r][1] = fmaf(xv.x, w0.y, fmaf(xv.y, w1.y, fmaf(xv.z, w2.y, fmaf(xv.w, w3.y, acc[r][1]))));
      acc[r][2] = fmaf(xv.x, w0.z, fmaf(xv.y, w1.z, fmaf(xv.z, w2.z, fmaf(xv.w, w3.z, acc[r][2]))));
      acc[r][3] = fmaf(xv.x, w0.w, fmaf(xv.y, w1.w, fmaf(xv.z, w2.w, fmaf(xv.w, w3.w, acc[r][3]))));
    }
  }
  float4 bias = *(const float4*)&b2[c4*4];
#pragma unroll
  for (int r = 0; r < 4; ++r) {
    float4 o = make_float4(acc[r][0]+bias.x, acc[r][1]+bias.y, acc[r][2]+bias.z, acc[r][3]+bias.w);
    *(float4*)&out[(size_t)(row0 + rg*4 + r)*COUT + c4*4] = o;
  }
}

extern "C" void kernel_launch(void* const* d_in, const int* in_sizes, int n_in,
                              void* d_out, int out_size, void* d_ws, size_t ws_size,
                              hipStream_t stream) {
  const float* x  = (const float*)d_in[0];
  const float* Ws = (const float*)d_in[1];
  const float* bs = (const float*)d_in[2];
  const float* Wh = (const float*)d_in[3];
  const float* bh = (const float*)d_in[4];
  const float* W1 = (const float*)d_in[5];
  const float* W2 = (const float*)d_in[6];
  const float* b2 = (const float*)d_in[7];
  float* out = (float*)d_out;

  char* ws = (char*)d_ws;
  float4* s4 = (float4*)(ws + WS_S4);
  float*  h  = (float*) (ws + WS_H);

  k1_proj<<<NPTS/64, 256, 0, stream>>>(x, Ws, bs, Wh, bh, s4, h);

  if (ws_size >= (size_t)WS_NEED_M) {
    float* t2  = (float*)(ws + WS_T2);
    float* agg = (float*)(ws + WS_AGG_M);
    float* wT  = (float*)(ws + WS_WT_M);
    uint*  mw  = (uint*) (ws + WS_MASK);
    k2t_thresh<<<NPTS/16, 256, 0, stream>>>(s4, t2);
    k2b_mask<<<1024, 256, 0, stream>>>(s4, t2, mw);
    k3_sel<<<NPTS/16, 256, 0, stream>>>(s4, h, (const uint4*)mw, agg);
    k4a_wt<<<(192*COUT + 255)/256, 256, 0, stream>>>(W1, W2, wT);
    k4_out2<<<NPTS/32, 256, 0, stream>>>(x, agg, wT, b2, out);
  } else {
    unsigned short* cj = (unsigned short*)(ws + WS_CJ_F);
    float* agg = (float*)(ws + WS_AGG_F);
    float* wT  = (float*)(ws + WS_WT_F);
    k2_knn_fb<<<512, 256, 0, stream>>>(s4, cj);
    k3_merge_fb<<<NPTS/64, 256, 0, stream>>>(s4, (const float4*)h, cj, agg);
    k4a_wt<<<(192*COUT + 255)/256, 256, 0, stream>>>(W1, W2, wT);
    k4_out2<<<NPTS/32, 256, 0, stream>>>(x, agg, wT, b2, out);
  }
}

// Round 6
// 237.060 us; speedup vs baseline: 2.3952x; 1.0683x over previous
//
#include <hip/hip_runtime.h>
#include <hip/hip_bf16.h>

// GravNetConv: N=16384, C_IN=128, S=4, P=32, K=16, C_OUT=128.
// Mask path: [k1] proj (fp64 s) -> [k2t] threshold via radix-ladder histogram ->
// [k2b] full N^2 scan -> bitmask via GRAM-form test (si.sj - bj >= ui, 6 VALU/pair,
// margin absorbs cancellation; k3 re-ranks with exact direct d2) -> [k3_sel] recovery
// + 16-lane tournament + fused aggregation -> [k4a/k4_out2] out = x@W1^T + agg@W2^T + b2.
// Fallback path (ws_size < 41MB): round-2 kernels.

#define NPTS 16384
#define CIN  128
#define SD   4
#define PD   32
#define KNN  16
#define COUT 128
#define FLTMAX 3.4028234663852886e+38f
#define CCAP 48
#define CSTR 50
#define NBIN 33

typedef float v2f __attribute__((ext_vector_type(2)));
typedef unsigned int uint;

// ---- shared offsets (both paths) ----
#define WS_S4     0            // N * float4 = 256 KB
#define WS_H      0x40000      // N * 32 f32 = 2 MB
// ---- mask-path offsets ----
#define WS_AGG_M  0x280000     // [N][64] f32 = 4 MB
#define WS_WT_M   0x680000     // [192][128] f32 = 96 KB
#define WS_T2     0x6A0000     // N f32 = 64 KB
#define WS_MASK   0x700000     // 128 chunks * N * 4 words u32 = 32 MB
#define WS_NEED_M 0x2700000    // 40.9 MB
// ---- fallback offsets ----
#define WS_CJ_F   0x400000
#define WS_AGG_F  0xC00000
#define WS_WT_F   0x1000000
#define JS   16
#define TJF  (NPTS/JS)

__device__ __forceinline__ float d2f(const float4 a, const float4 b) {
  v2f d0 = {a.x - b.x, a.y - b.y};
  v2f d1 = {a.z - b.z, a.w - b.w};
  v2f pr = d0*d0 + d1*d1;
  return pr.x + pr.y;
}

// ---------------- Kernel 1: s (fp64 accumulate) and h projections ----------------
__global__ __launch_bounds__(256) void k1_proj(
    const float* __restrict__ x, const float* __restrict__ Ws, const float* __restrict__ bs,
    const float* __restrict__ Wh, const float* __restrict__ bh,
    float4* __restrict__ s4, float* __restrict__ h) {
  __shared__ float  lw[36*128];
  __shared__ float  lx[64*132];
  __shared__ double rs[3*64*5];
  __shared__ float  rh[3*64*33];
  const int t = threadIdx.x;
  const int row0 = blockIdx.x * 64;
  for (int i2 = t; i2 < 36*128; i2 += 256)
    lw[i2] = (i2 < 512) ? Ws[i2] : Wh[i2 - 512];
#pragma unroll
  for (int g = 0; g < 8; ++g) {
    int fi = g*256 + t;
    int r = fi >> 5, c4 = fi & 31;
    *(float4*)&lx[r*132 + c4*4] = *(const float4*)&x[(size_t)(row0 + r)*CIN + c4*4];
  }
  __syncthreads();
  const int kq = t >> 6;
  const int r  = t & 63;
  const int kb = kq * 32;
  double sacc[4] = {0.0, 0.0, 0.0, 0.0};
  float  hacc[32];
#pragma unroll
  for (int p = 0; p < 32; ++p) hacc[p] = 0.f;
#pragma unroll
  for (int k4 = 0; k4 < 8; ++k4) {
    float4 xv = *(const float4*)&lx[r*132 + kb + k4*4];
    int kg = kb + k4*4;
#pragma unroll
    for (int p = 0; p < 4; ++p) {
      float4 wv = *(const float4*)&lw[p*128 + kg];
      sacc[p] = fma((double)xv.x, (double)wv.x, sacc[p]);
      sacc[p] = fma((double)xv.y, (double)wv.y, sacc[p]);
      sacc[p] = fma((double)xv.z, (double)wv.z, sacc[p]);
      sacc[p] = fma((double)xv.w, (double)wv.w, sacc[p]);
    }
#pragma unroll
    for (int p = 0; p < 32; ++p) {
      float4 wv = *(const float4*)&lw[(4+p)*128 + kg];
      hacc[p] = fmaf(xv.x, wv.x, fmaf(xv.y, wv.y, fmaf(xv.z, wv.z, fmaf(xv.w, wv.w, hacc[p]))));
    }
  }
  if (kq > 0) {
    const int bq = kq - 1;
#pragma unroll
    for (int d = 0; d < 4; ++d) rs[(bq*64 + r)*5 + d] = sacc[d];
#pragma unroll
    for (int p = 0; p < 32; ++p) rh[(bq*64 + r)*33 + p] = hacc[p];
  }
  __syncthreads();
  if (kq == 0) {
    const int row = row0 + r;
    float so[4];
#pragma unroll
    for (int d = 0; d < 4; ++d) {
      double sd = sacc[d] + rs[(0*64 + r)*5 + d] + rs[(1*64 + r)*5 + d]
                + rs[(2*64 + r)*5 + d] + (double)bs[d];
      so[d] = (float)sd;
    }
    s4[row] = make_float4(so[0], so[1], so[2], so[3]);
#pragma unroll
    for (int p4 = 0; p4 < 8; ++p4) {
      float o[4];
#pragma unroll
      for (int c = 0; c < 4; ++c) {
        int p = p4*4 + c;
        o[c] = hacc[p] + rh[(0*64 + r)*33 + p] + rh[(1*64 + r)*33 + p]
             + rh[(2*64 + r)*33 + p] + bh[p];
      }
      *(float4*)&h[(size_t)row*PD + p4*4] = make_float4(o[0], o[1], o[2], o[3]);
    }
  }
}

// ---------------- Kernel 2t: per-query threshold via radix-ladder histogram ----------------
__global__ __launch_bounds__(256) void k2t_thresh(
    const float4* __restrict__ s4, float* __restrict__ t2) {
  __shared__ float4 tile[2064];
  __shared__ uint   lhist[256*NBIN];
  const int t = threadIdx.x;
#pragma unroll
  for (int g = 0; g < 8; ++g) {
    int j = g*256 + t;
    tile[j + (j >> 7)] = s4[j];
  }
#pragma unroll
  for (int b = 0; b < NBIN; ++b) lhist[t*NBIN + b] = 0u;
  const int ql = t >> 4, tq = t & 15;
  const int q  = blockIdx.x*16 + ql;
  const float4 sq = s4[q];
  __syncthreads();
  float tau = d2f(sq, tile[tq*129]);
#pragma unroll
  for (int m = 1; m < 16; m <<= 1) tau = fmaxf(tau, __shfl_xor(tau, m, 16));
  const int ktop = (int)(__float_as_uint(tau) >> 21);
  const int hb = t*NBIN;
#pragma unroll 4
  for (int u = 0; u < 128; ++u) {
    float4 p = tile[tq*129 + u];
    float e = d2f(sq, p);
    int key = (int)(__float_as_uint(e) >> 21);
    int rel = ktop - key;
    rel = rel < 0 ? 0 : (rel > 32 ? 32 : rel);
    atomicAdd(&lhist[hb + rel], 1u);
  }
  __syncthreads();
  uint c0 = 0, c1 = 0;
  const int qb = ql*16;
  for (int u = 0; u < 16; ++u) {
    c0 += lhist[(qb + u)*NBIN + tq*2];
    c1 += (tq*2 + 1 < NBIN) ? lhist[(qb + u)*NBIN + tq*2 + 1] : 0u;
  }
  int S = (int)(c0 + c1);
#pragma unroll
  for (int d = 1; d < 16; d <<= 1) {
    int v = __shfl_down(S, d, 16);
    S += (tq + d < 16) ? v : 0;
  }
  int g = -1;
  if (S >= KNN) g = 2*tq;
  if (S - (int)c0 >= KNN) g = 2*tq + 1;
#pragma unroll
  for (int m = 1; m < 16; m <<= 1) g = max(g, __shfl_xor(g, m, 16));
  if (tq == 0) {
    uint K = (uint)(ktop - g);
    t2[q] = __uint_as_float((K << 21) | 0x1FFFFFu);
  }
}

// ---------------- Kernel 2b: full scan -> bitmask via Gram-form test ----------------
// d2 <= t2+eps  <=>  si.sj - bj >= ui,  bj = |sj|^2/2 (staged), ui = (|si|^2 - t2)/2 - eps/2.
// 4-deep fma chain + cmp + addc = 6 VALU/pair. Margin only loosens the superset mask;
// k3 re-ranks with exact direct-form d2.
__global__ __launch_bounds__(256) void k2b_mask(
    const float4* __restrict__ s4, const float* __restrict__ t2, uint* __restrict__ maskw) {
  __shared__ float4 tile4[128];
  __shared__ float  tileb[128];
  const int t  = threadIdx.x;
  const int c  = blockIdx.x >> 3;   // 128 chunks
  const int ig = blockIdx.x & 7;    // 8 query groups of 2048
  if (t < 128) {
    float4 p = s4[c*128 + t];
    tile4[t] = p;
    tileb[t] = 0.5f*(p.x*p.x + p.y*p.y + p.z*p.z + p.w*p.w);
  }
  const int q0 = ig*2048 + t;
  float4 sq[8]; float ui[8];
#pragma unroll
  for (int m = 0; m < 8; ++m) {
    int q = q0 + m*256;
    float4 s = s4[q];
    sq[m] = s;
    float n2 = s.x*s.x + s.y*s.y + s.z*s.z + s.w*s.w;
    ui[m] = 0.5f*(n2 - t2[q]) - 4e-6f;
  }
  __syncthreads();
#pragma unroll 1
  for (int w = 0; w < 4; ++w) {
    uint msk[8];
#pragma unroll
    for (int m = 0; m < 8; ++m) msk[m] = 0u;
#pragma unroll
    for (int bit = 31; bit >= 0; --bit) {
      float4 p = tile4[w*32 + bit];
      float nb = tileb[w*32 + bit];
#pragma unroll
      for (int m = 0; m < 8; ++m) {
        float acc = fmaf(sq[m].x, p.x, fmaf(sq[m].y, p.y,
                    fmaf(sq[m].z, p.z, fmaf(sq[m].w, p.w, -nb))));
        msk[m] = msk[m] + msk[m] + (acc >= ui[m] ? 1u : 0u);
      }
    }
#pragma unroll
    for (int m = 0; m < 8; ++m) {
      int q = q0 + m*256;
      maskw[((size_t)c*NPTS + q)*4 + w] = msk[m];
    }
  }
}

// ---------------- Kernel 3: phased recovery + tournament + fused aggregation ----------------
__global__ __launch_bounds__(256) void k3_sel(
    const float4* __restrict__ s4, const float* __restrict__ h,
    const uint4* __restrict__ maskw, float* __restrict__ agg) {
  __shared__ unsigned short cand[256*CSTR];
  const int t  = threadIdx.x;
  const int ql = t >> 4, tq = t & 15;
  const int q  = blockIdx.x*16 + ql;
  const float4 sq = s4[q];
  int cnt = 0;
#pragma unroll
  for (int b2 = 0; b2 < 2; ++b2) {
    uint4 mw[4];
#pragma unroll
    for (int u = 0; u < 4; ++u) {
      int c = tq*8 + b2*4 + u;
      mw[u] = maskw[(size_t)c*NPTS + q];
    }
#pragma unroll
    for (int u = 0; u < 4; ++u) {
      int c = tq*8 + b2*4 + u;
      uint wv[4] = {mw[u].x, mw[u].y, mw[u].z, mw[u].w};
#pragma unroll
      for (int w = 0; w < 4; ++w) {
        uint bits = wv[w];
        while (bits) {
          int b = __builtin_ctz(bits); bits &= bits - 1;
          if (cnt < CCAP) cand[t*CSTR + cnt] = (unsigned short)(c*128 + w*32 + b);
          ++cnt;
        }
      }
    }
  }
  cnt = cnt < CCAP ? cnt : CCAP;
  float val[KNN]; int vid[KNN];
#pragma unroll
  for (int u = 0; u < KNN; ++u) { val[u] = FLTMAX; vid[u] = 0x3FFFFFFF; }
  float cmax = FLTMAX; int cpos = 0;
  for (int u0 = 0; u0 < cnt; u0 += 4) {       // dynamic bound: avg cnt ~9, was fixed 48
    int jj[4]; float4 pj[4];
#pragma unroll
    for (int v = 0; v < 4; ++v) {
      int uu = u0 + v;
      jj[v] = (uu < cnt) ? (int)cand[t*CSTR + uu] : -1;
      pj[v] = s4[jj[v] < 0 ? 0 : jj[v]];
    }
#pragma unroll
    for (int v = 0; v < 4; ++v) {
      float e = (jj[v] >= 0) ? d2f(sq, pj[v]) : FLTMAX;
      if (e < cmax) {
#pragma unroll
        for (int u = 0; u < KNN; ++u) if (u == cpos) { val[u] = e; vid[u] = jj[v]; }
        cmax = val[0]; cpos = 0;
#pragma unroll
        for (int u = 1; u < KNN; ++u) { if (val[u] > cmax) { cmax = val[u]; cpos = u; } }
      }
    }
  }
  float msum0 = 0.f, msum1 = 0.f, mmax0 = -FLTMAX, mmax1 = -FLTMAX;
#pragma unroll 1
  for (int r = 0; r < KNN; ++r) {
    float bd = val[0]; int bj = vid[0];
#pragma unroll
    for (int u = 1; u < KNN; ++u) {
      bool lt = (val[u] < bd) || (val[u] == bd && vid[u] < bj);
      bd = lt ? val[u] : bd; bj = lt ? vid[u] : bj;
    }
    float rd = bd; int rj = bj;
#pragma unroll
    for (int m = 1; m < 16; m <<= 1) {
      float od = __shfl_xor(rd, m, 64);
      int   oj = __shfl_xor(rj, m, 64);
      bool lt = (od < rd) || (od == rd && oj < rj);
      rd = lt ? od : rd; rj = lt ? oj : rj;
    }
    bool mine = (bd == rd) && (bj == rj);
#pragma unroll
    for (int u = 0; u < KNN; ++u) {
      bool kill = mine && (val[u] == rd) && (vid[u] == rj);
      val[u] = kill ? FLTMAX : val[u];
      vid[u] = kill ? 0x3FFFFFFF : vid[u];
    }
    float w = __expf(-10.f * rd);
    float2 hv = *(const float2*)&h[(size_t)rj*PD + tq*2];
    float m0 = hv.x*w, m1 = hv.y*w;
    msum0 += m0; msum1 += m1;
    mmax0 = fmaxf(mmax0, m0); mmax1 = fmaxf(mmax1, m1);
  }
  *(float2*)&agg[(size_t)q*64 + tq*2]      = make_float2(msum0*0.0625f, msum1*0.0625f);
  *(float2*)&agg[(size_t)q*64 + 32 + tq*2] = make_float2(mmax0, mmax1);
}

// ================= Fallback path (round-2, proven) =================
__global__ __launch_bounds__(256) void k2_knn_fb(
    const float4* __restrict__ s4, unsigned short* __restrict__ cand_j) {
  __shared__ float4 tile[TJF];
  __shared__ int    lbuf[256*33];
  const int t  = threadIdx.x;
  const int ib = blockIdx.x & 31;
  const int jc = blockIdx.x >> 5;
  const int jbase = jc * TJF;
#pragma unroll
  for (int g = 0; g < 4; ++g) tile[g*256 + t] = s4[jbase + g*256 + t];
  const int ia = ib*256 + t;
  const int ic = ia + 8192;
  const float4 sa = s4[ia];
  const float4 sc = s4[ic];
  __syncthreads();
  float va[KNN], vb[KNN]; int ja[KNN], jb[KNN];
#pragma unroll
  for (int q = 0; q < KNN; ++q) { va[q] = FLTMAX; ja[q] = 0; vb[q] = FLTMAX; jb[q] = 0; }
  float cma = FLTMAX, cmb = FLTMAX;
  int cpa = 0, cpb = 0, ca = 0, cb = 0;
  auto insertA = [&](float e, int jj) {
#pragma unroll
    for (int q = 0; q < KNN; ++q) if (q == cpa) { va[q] = e; ja[q] = jj; }
    cma = va[0]; cpa = 0;
#pragma unroll
    for (int q = 1; q < KNN; ++q) { if (va[q] > cma) { cma = va[q]; cpa = q; } }
  };
  auto insertB = [&](float e, int jj) {
#pragma unroll
    for (int q = 0; q < KNN; ++q) if (q == cpb) { vb[q] = e; jb[q] = jj; }
    cmb = vb[0]; cpb = 0;
#pragma unroll
    for (int q = 1; q < KNN; ++q) { if (vb[q] > cmb) { cmb = vb[q]; cpb = q; } }
  };
  auto compactA = [&]() {
    for (int u = 0; u < ca; ++u) {
      int jj = lbuf[t*33 + u];
      float e = d2f(sa, tile[jj]);
      if (e < cma) insertA(e, jj);
    }
    ca = 0;
  };
  auto compactB = [&]() {
    for (int u = 0; u < cb; ++u) {
      int jj = lbuf[t*33 + 16 + u];
      float e = d2f(sc, tile[jj]);
      if (e < cmb) insertB(e, jj);
    }
    cb = 0;
  };
  for (int ob = 0; ob < TJF/8; ++ob) {
#pragma unroll
    for (int u = 0; u < 8; ++u) {
      int jj = ob*8 + u;
      float4 p = tile[jj];
      float ea = d2f(sa, p);
      float eb = d2f(sc, p);
      if (ea < cma) { lbuf[t*33 + ca] = jj; ++ca; }
      if (eb < cmb) { lbuf[t*33 + 16 + cb] = jj; ++cb; }
    }
    if (__any(ca > 8)) compactA();
    if (__any(cb > 8)) compactB();
  }
  compactA(); compactB();
#pragma unroll
  for (int q = 0; q < KNN; ++q) {
    int c = jc*KNN + q;
    cand_j[(size_t)c*NPTS + ia] = (unsigned short)(ja[q] + jbase);
    cand_j[(size_t)c*NPTS + ic] = (unsigned short)(jb[q] + jbase);
  }
}

__global__ __launch_bounds__(256) void k3_merge_fb(
    const float4* __restrict__ s4, const float4* __restrict__ h4,
    const unsigned short* __restrict__ cand_j, float* __restrict__ agg) {
  __shared__ float le[64*67];
  __shared__ int   lj[64*67];
  const int t  = threadIdx.x;
  const int il = t & 63, tq = t >> 6;
  const int i  = blockIdx.x*64 + il;
  const float4 si = s4[i];
  float val[KNN]; int vid[KNN];
#pragma unroll
  for (int q = 0; q < KNN; ++q) { val[q] = FLTMAX; vid[q] = 0; }
  float cmax = FLTMAX; int cpos = 0;
  for (int u = 0; u < 64; ++u) {
    int c = tq*64 + u;
    int j = cand_j[(size_t)c*NPTS + i];
    float e = d2f(si, s4[j]);
    if (e < cmax) {
#pragma unroll
      for (int q = 0; q < KNN; ++q) if (q == cpos) { val[q] = e; vid[q] = j; }
      cmax = val[0]; cpos = 0;
#pragma unroll
      for (int q = 1; q < KNN; ++q) { if (val[q] > cmax) { cmax = val[q]; cpos = q; } }
    }
  }
#pragma unroll
  for (int q = 0; q < KNN; ++q) {
    le[il*67 + tq*16 + q] = val[q];
    lj[il*67 + tq*16 + q] = vid[q];
  }
  __syncthreads();
  if (t < 64) {
    float mv[KNN]; int mj[KNN];
#pragma unroll
    for (int q = 0; q < KNN; ++q) { mv[q] = FLTMAX; mj[q] = 0; }
    float cm2 = FLTMAX; int cp2 = 0;
    for (int u = 0; u < 64; ++u) {
      float e = le[t*67 + u];
      int   j = lj[t*67 + u];
      if (e < cm2) {
#pragma unroll
        for (int q = 0; q < KNN; ++q) if (q == cp2) { mv[q] = e; mj[q] = j; }
        cm2 = mv[0]; cp2 = 0;
#pragma unroll
        for (int q = 1; q < KNN; ++q) { if (mv[q] > cm2) { cm2 = mv[q]; cp2 = q; } }
      }
    }
#pragma unroll
    for (int q = 0; q < KNN; ++q) {
      le[t*67 + q] = __expf(-10.f * mv[q]);
      lj[t*67 + q] = mj[q];
    }
  }
  __syncthreads();
  float ms[8], mm[8];
#pragma unroll
  for (int p = 0; p < 8; ++p) { ms[p] = 0.f; mm[p] = -FLTMAX; }
#pragma unroll 1
  for (int q = 0; q < KNN; ++q) {
    float w = le[il*67 + q];
    int   j = lj[il*67 + q];
    float4 a = h4[(size_t)j*8 + tq*2];
    float4 b = h4[(size_t)j*8 + tq*2 + 1];
    float m0 = a.x*w, m1 = a.y*w, m2 = a.z*w, m3 = a.w*w;
    float m4 = b.x*w, m5 = b.y*w, m6 = b.z*w, m7 = b.w*w;
    ms[0] += m0; mm[0] = fmaxf(mm[0], m0);
    ms[1] += m1; mm[1] = fmaxf(mm[1], m1);
    ms[2] += m2; mm[2] = fmaxf(mm[2], m2);
    ms[3] += m3; mm[3] = fmaxf(mm[3], m3);
    ms[4] += m4; mm[4] = fmaxf(mm[4], m4);
    ms[5] += m5; mm[5] = fmaxf(mm[5], m5);
    ms[6] += m6; mm[6] = fmaxf(mm[6], m6);
    ms[7] += m7; mm[7] = fmaxf(mm[7], m7);
  }
  float4 o0 = make_float4(ms[0]*0.0625f, ms[1]*0.0625f, ms[2]*0.0625f, ms[3]*0.0625f);
  float4 o1 = make_float4(ms[4]*0.0625f, ms[5]*0.0625f, ms[6]*0.0625f, ms[7]*0.0625f);
  *(float4*)&agg[(size_t)i*64 + tq*8]      = o0;
  *(float4*)&agg[(size_t)i*64 + tq*8 + 4]  = o1;
  *(float4*)&agg[(size_t)i*64 + 32 + tq*8]     = make_float4(mm[0], mm[1], mm[2], mm[3]);
  *(float4*)&agg[(size_t)i*64 + 32 + tq*8 + 4] = make_float4(mm[4], mm[5], mm[6], mm[7]);
}

// ---------------- Kernel 4a: pack/transpose weights ----------------
__global__ __launch_bounds__(256) void k4a_wt(
    const float* __restrict__ W1, const float* __restrict__ W2, float* __restrict__ wT) {
  int idx = blockIdx.x*256 + threadIdx.x;
  if (idx >= 192*COUT) return;
  int k = idx >> 7, c = idx & 127;
  float v = (k < 128) ? W1[(size_t)c*128 + k] : W2[(size_t)c*64 + (k - 128)];
  wT[(size_t)k*COUT + c] = v;
}

// ---------------- Kernel 4: out = x@W1^T + agg@W2^T + b2 (32x128 tile, 4x4/thread) ----------
__global__ __launch_bounds__(256) void k4_out2(
    const float* __restrict__ x, const float* __restrict__ agg,
    const float* __restrict__ wT, const float* __restrict__ b2,
    float* __restrict__ out) {
  __shared__ float xa[32*192];
  const int t = threadIdx.x;
  const int row0 = blockIdx.x * 32;
#pragma unroll
  for (int g = 0; g < 4; ++g) {
    int fi = g*256 + t;
    int r = fi >> 5, c4 = fi & 31;
    *(float4*)&xa[r*192 + c4*4] = *(const float4*)&x[(size_t)(row0+r)*CIN + c4*4];
  }
#pragma unroll
  for (int g = 0; g < 2; ++g) {
    int fi = g*256 + t;
    int r = fi >> 4, c4 = fi & 15;
    *(float4*)&xa[r*192 + 128 + c4*4] = *(const float4*)&agg[(size_t)(row0+r)*64 + c4*4];
  }
  __syncthreads();
  const int c4 = t & 31;
  const int rg = t >> 5;
  float acc[4][4];
#pragma unroll
  for (int r = 0; r < 4; ++r) { acc[r][0]=0.f; acc[r][1]=0.f; acc[r][2]=0.f; acc[r][3]=0.f; }
  for (int k = 0; k < 192; k += 4) {
    float4 w0 = *(const float4*)&wT[(size_t)(k+0)*COUT + c4*4];
    float4 w1 = *(const float4*)&wT[(size_t)(k+1)*COUT + c4*4];
    float4 w2 = *(const float4*)&wT[(size_t)(k+2)*COUT + c4*4];
    float4 w3 = *(const float4*)&wT[(size_t)(k+3)*COUT + c4*4];
#pragma unroll
    for (int r = 0; r < 4; ++r) {
      float4 xv = *(const float4*)&xa[(rg*4 + r)*192 + k];
      acc[r][0] = fmaf(xv.x, w0.x, fmaf(xv.y, w1.x, fmaf(xv.z, w2.x, fmaf(xv.w, w3.x, acc[r][0]))));
      acc[r][1] = fmaf(xv.x, w0.y, fmaf(xv.y, w1.y, fmaf(xv.z, w2.y, fmaf(xv.w, w3.y, acc[r][1]))));
      acc[r][2] = fmaf(xv.x, w0.z, fmaf(xv.y, w1.z, fmaf(xv.z, w2.z, fmaf(xv.w, w3.z, acc[r][2]))));
      acc[r][3] = fmaf(xv.x, w0.w, fmaf(xv.y, w1.w, fmaf(xv.z, w2.w, fmaf(xv.w, w3.w, acc[r][3]))));
    }
  }
  float4 bias = *(const float4*)&b2[c4*4];
#pragma unroll
  for (int r = 0; r < 4; ++r) {
    float4 o = make_float4(acc[r][0]+bias.x, acc[r][1]+bias.y, acc[r][2]+bias.z, acc[r][3]+bias.w);
    *(float4*)&out[(size_t)(row0 + rg*4 + r)*COUT + c4*4] = o;
  }
}

extern "C" void kernel_launch(void* const* d_in, const int* in_sizes, int n_in,
                              void* d_out, int out_size, void* d_ws, size_t ws_size,
                              hipStream_t stream) {
  const float* x  = (const float*)d_in[0];
  const float* Ws = (const float*)d_in[1];
  const float* bs = (const float*)d_in[2];
  const float* Wh = (const float*)d_in[3];
  const float* bh = (const float*)d_in[4];
  const float* W1 = (const float*)d_in[5];
  const float* W2 = (const float*)d_in[6];
  const float* b2 = (const float*)d_in[7];
  float* out = (float*)d_out;

  char* ws = (char*)d_ws;
  float4* s4 = (float4*)(ws + WS_S4);
  float*  h  = (float*) (ws + WS_H);

  k1_proj<<<NPTS/64, 256, 0, stream>>>(x, Ws, bs, Wh, bh, s4, h);

  if (ws_size >= (size_t)WS_NEED_M) {
    float* t2  = (float*)(ws + WS_T2);
    float* agg = (float*)(ws + WS_AGG_M);
    float* wT  = (float*)(ws + WS_WT_M);
    uint*  mw  = (uint*) (ws + WS_MASK);
    k2t_thresh<<<NPTS/16, 256, 0, stream>>>(s4, t2);
    k2b_mask<<<1024, 256, 0, stream>>>(s4, t2, mw);
    k3_sel<<<NPTS/16, 256, 0, stream>>>(s4, h, (const uint4*)mw, agg);
    k4a_wt<<<(192*COUT + 255)/256, 256, 0, stream>>>(W1, W2, wT);
    k4_out2<<<NPTS/32, 256, 0, stream>>>(x, agg, wT, b2, out);
  } else {
    unsigned short* cj = (unsigned short*)(ws + WS_CJ_F);
    float* agg = (float*)(ws + WS_AGG_F);
    float* wT  = (float*)(ws + WS_WT_F);
    k2_knn_fb<<<512, 256, 0, stream>>>(s4, cj);
    k3_merge_fb<<<NPTS/64, 256, 0, stream>>>(s4, (const float4*)h, cj, agg);
    k4a_wt<<<(192*COUT + 255)/256, 256, 0, stream>>>(W1, W2, wT);
    k4_out2<<<NPTS/32, 256, 0, stream>>>(x, agg, wT, b2, out);
  }
}

// Round 8
// 220.936 us; speedup vs baseline: 2.5700x; 1.0730x over previous
//
#include <hip/hip_runtime.h>
#include <hip/hip_bf16.h>

// GravNetConv: N=16384, C_IN=128, S=4, P=32, K=16, C_OUT=128.
// Mask path: [k1] proj (fp64 s) -> [k2t] threshold via radix-ladder histogram ->
// [k2b] full N^2 scan -> bitmask (Gram-form, pk_fma, 4 queries/thread, grid 2048) ->
// [k3_sel2] rank-based recovery (kmax-anchored class histogram; clamp-consistent
// qualifier predicate) -> coalesced aggregation -> [k4a/k4_out2] output GEMM.
// Fallback path (ws_size < 41MB): round-2 kernels.

#define NPTS 16384
#define CIN  128
#define SD   4
#define PD   32
#define KNN  16
#define COUT 128
#define FLTMAX 3.4028234663852886e+38f
#define NBIN 33
#define QPB  8      // k3 queries per block
#define QCAP 512    // k3 per-query candidate cap
#define MCAP 128    // k3 per-query qualifier cap (fallback scan if exceeded)

typedef float v2f __attribute__((ext_vector_type(2)));
typedef unsigned int uint;
typedef unsigned long long u64;

// ---- shared offsets (both paths) ----
#define WS_S4     0            // N * float4 = 256 KB
#define WS_H      0x40000      // N * 32 f32 = 2 MB
// ---- mask-path offsets ----
#define WS_AGG_M  0x280000     // [N][64] f32 = 4 MB
#define WS_WT_M   0x680000     // [192][128] f32 = 96 KB
#define WS_T2     0x6A0000     // N f32 = 64 KB
#define WS_MASK   0x700000     // 128 chunks * N * 4 words u32 = 32 MB
#define WS_NEED_M 0x2700000    // 40.9 MB
// ---- fallback offsets ----
#define WS_CJ_F   0x400000
#define WS_AGG_F  0xC00000
#define WS_WT_F   0x1000000
#define JS   16
#define TJF  (NPTS/JS)

__device__ __forceinline__ float d2f(const float4 a, const float4 b) {
  v2f d0 = {a.x - b.x, a.y - b.y};
  v2f d1 = {a.z - b.z, a.w - b.w};
  v2f pr = d0*d0 + d1*d1;
  return pr.x + pr.y;
}

// ---------------- Kernel 1: s (fp64 accumulate) and h projections ----------------
__global__ __launch_bounds__(256) void k1_proj(
    const float* __restrict__ x, const float* __restrict__ Ws, const float* __restrict__ bs,
    const float* __restrict__ Wh, const float* __restrict__ bh,
    float4* __restrict__ s4, float* __restrict__ h) {
  __shared__ float  lw[36*128];
  __shared__ float  lx[64*132];
  __shared__ double rs[3*64*5];
  __shared__ float  rh[3*64*33];
  const int t = threadIdx.x;
  const int row0 = blockIdx.x * 64;
  for (int i2 = t; i2 < 36*128; i2 += 256)
    lw[i2] = (i2 < 512) ? Ws[i2] : Wh[i2 - 512];
#pragma unroll
  for (int g = 0; g < 8; ++g) {
    int fi = g*256 + t;
    int r = fi >> 5, c4 = fi & 31;
    *(float4*)&lx[r*132 + c4*4] = *(const float4*)&x[(size_t)(row0 + r)*CIN + c4*4];
  }
  __syncthreads();
  const int kq = t >> 6;
  const int r  = t & 63;
  const int kb = kq * 32;
  double sacc[4] = {0.0, 0.0, 0.0, 0.0};
  float  hacc[32];
#pragma unroll
  for (int p = 0; p < 32; ++p) hacc[p] = 0.f;
#pragma unroll
  for (int k4 = 0; k4 < 8; ++k4) {
    float4 xv = *(const float4*)&lx[r*132 + kb + k4*4];
    int kg = kb + k4*4;
#pragma unroll
    for (int p = 0; p < 4; ++p) {
      float4 wv = *(const float4*)&lw[p*128 + kg];
      sacc[p] = fma((double)xv.x, (double)wv.x, sacc[p]);
      sacc[p] = fma((double)xv.y, (double)wv.y, sacc[p]);
      sacc[p] = fma((double)xv.z, (double)wv.z, sacc[p]);
      sacc[p] = fma((double)xv.w, (double)wv.w, sacc[p]);
    }
#pragma unroll
    for (int p = 0; p < 32; ++p) {
      float4 wv = *(const float4*)&lw[(4+p)*128 + kg];
      hacc[p] = fmaf(xv.x, wv.x, fmaf(xv.y, wv.y, fmaf(xv.z, wv.z, fmaf(xv.w, wv.w, hacc[p]))));
    }
  }
  if (kq > 0) {
    const int bq = kq - 1;
#pragma unroll
    for (int d = 0; d < 4; ++d) rs[(bq*64 + r)*5 + d] = sacc[d];
#pragma unroll
    for (int p = 0; p < 32; ++p) rh[(bq*64 + r)*33 + p] = hacc[p];
  }
  __syncthreads();
  if (kq == 0) {
    const int row = row0 + r;
    float so[4];
#pragma unroll
    for (int d = 0; d < 4; ++d) {
      double sd = sacc[d] + rs[(0*64 + r)*5 + d] + rs[(1*64 + r)*5 + d]
                + rs[(2*64 + r)*5 + d] + (double)bs[d];
      so[d] = (float)sd;
    }
    s4[row] = make_float4(so[0], so[1], so[2], so[3]);
#pragma unroll
    for (int p4 = 0; p4 < 8; ++p4) {
      float o[4];
#pragma unroll
      for (int c = 0; c < 4; ++c) {
        int p = p4*4 + c;
        o[c] = hacc[p] + rh[(0*64 + r)*33 + p] + rh[(1*64 + r)*33 + p]
             + rh[(2*64 + r)*33 + p] + bh[p];
      }
      *(float4*)&h[(size_t)row*PD + p4*4] = make_float4(o[0], o[1], o[2], o[3]);
    }
  }
}

// ---------------- Kernel 2t: per-query threshold via radix-ladder histogram ----------------
__global__ __launch_bounds__(256) void k2t_thresh(
    const float4* __restrict__ s4, float* __restrict__ t2) {
  __shared__ float4 tile[2064];
  __shared__ uint   lhist[256*NBIN];
  const int t = threadIdx.x;
#pragma unroll
  for (int g = 0; g < 8; ++g) {
    int j = g*256 + t;
    tile[j + (j >> 7)] = s4[j];
  }
#pragma unroll
  for (int b = 0; b < NBIN; ++b) lhist[t*NBIN + b] = 0u;
  const int ql = t >> 4, tq = t & 15;
  const int q  = blockIdx.x*16 + ql;
  const float4 sq = s4[q];
  __syncthreads();
  float tau = d2f(sq, tile[tq*129]);
#pragma unroll
  for (int m = 1; m < 16; m <<= 1) tau = fmaxf(tau, __shfl_xor(tau, m, 16));
  const int ktop = (int)(__float_as_uint(tau) >> 21);
  const int hb = t*NBIN;
#pragma unroll 4
  for (int u = 0; u < 128; ++u) {
    float4 p = tile[tq*129 + u];
    float e = d2f(sq, p);
    int key = (int)(__float_as_uint(e) >> 21);
    int rel = ktop - key;
    rel = rel < 0 ? 0 : (rel > 32 ? 32 : rel);
    atomicAdd(&lhist[hb + rel], 1u);
  }
  __syncthreads();
  uint c0 = 0, c1 = 0;
  const int qb = ql*16;
  for (int u = 0; u < 16; ++u) {
    c0 += lhist[(qb + u)*NBIN + tq*2];
    c1 += (tq*2 + 1 < NBIN) ? lhist[(qb + u)*NBIN + tq*2 + 1] : 0u;
  }
  int S = (int)(c0 + c1);
#pragma unroll
  for (int d = 1; d < 16; d <<= 1) {
    int v = __shfl_down(S, d, 16);
    S += (tq + d < 16) ? v : 0;
  }
  int g = -1;
  if (S >= KNN) g = 2*tq;
  if (S - (int)c0 >= KNN) g = 2*tq + 1;
#pragma unroll
  for (int m = 1; m < 16; m <<= 1) g = max(g, __shfl_xor(g, m, 16));
  if (tq == 0) {
    uint K = (uint)(ktop - g);
    t2[q] = __uint_as_float((K << 21) | 0x1FFFFFu);
  }
}

// ---------------- Kernel 2b: full scan -> bitmask, Gram-form, pk_fma, M=4 ----------------
__global__ __launch_bounds__(256) void k2b_mask(
    const float4* __restrict__ s4, const float* __restrict__ t2, uint* __restrict__ maskw) {
  __shared__ float4 tile4[128];
  __shared__ float  tileb[128];
  const int t  = threadIdx.x;
  const int c  = blockIdx.x >> 4;   // 128 chunks
  const int ig = blockIdx.x & 15;   // 16 query groups of 1024
  if (t < 128) {
    float4 p = s4[c*128 + t];
    tile4[t] = p;
    tileb[t] = 0.5f*(p.x*p.x + p.y*p.y + p.z*p.z + p.w*p.w);
  }
  const int q0 = ig*1024 + t;
  v2f sxy[4], szw[4]; float ui[4];
#pragma unroll
  for (int m = 0; m < 4; ++m) {
    int q = q0 + m*256;
    float4 s = s4[q];
    sxy[m] = (v2f){s.x, s.y};
    szw[m] = (v2f){s.z, s.w};
    float n2 = s.x*s.x + s.y*s.y + s.z*s.z + s.w*s.w;
    ui[m] = 0.5f*(n2 - t2[q]) - 4e-6f;
  }
  __syncthreads();
#pragma unroll 1
  for (int w = 0; w < 4; ++w) {
    uint msk[4] = {0u, 0u, 0u, 0u};
#pragma unroll
    for (int bit = 31; bit >= 0; --bit) {
      float4 p = tile4[w*32 + bit];
      float nb = tileb[w*32 + bit];
      v2f pxy = (v2f){p.x, p.y};
      v2f pzw = (v2f){p.z, p.w};
      v2f nb2 = (v2f){-nb, 0.f};
#pragma unroll
      for (int m = 0; m < 4; ++m) {
        v2f a = szw[m]*pzw + nb2;
        v2f b = sxy[m]*pxy + a;
        float val = b.x + b.y;
        msk[m] = msk[m] + msk[m] + (val >= ui[m] ? 1u : 0u);
      }
    }
#pragma unroll
    for (int m = 0; m < 4; ++m) {
      int q = q0 + m*256;
      maskw[((size_t)c*NPTS + q)*4 + w] = msk[m];
    }
  }
}

// ---------------- Kernel 3: rank-based recovery + aggregation ----------------
// block = 8 queries x 32 lanes. Lane covers chunks [4*ln, 4*ln+4).
// Class window anchored at kmax (largest candidate class): rel = min(kmax-cls, 31).
// cum(r) = #(rel>=r) = #(cls <= kmax-r)  -- clamp-consistent with qualifier predicate.
__global__ __launch_bounds__(256) void k3_sel2(
    const float4* __restrict__ s4, const float* __restrict__ h,
    const uint4* __restrict__ maskw, float* __restrict__ agg) {
  __shared__ u64  qbuf[QPB*MCAP];       // 8 KB; aliased below as u16 j-list
  __shared__ u64  keys[QPB*QCAP];       // 32 KB
  __shared__ u64  win[QPB*KNN];         // 1 KB
  __shared__ uint hist[QPB*32];         // 1 KB
  __shared__ uint cnts[QPB];
  __shared__ uint mc[QPB];
  unsigned short* jl = (unsigned short*)qbuf;   // QPB*QCAP u16 = 8 KB (exact alias)
  const int t  = threadIdx.x;
  const int ql = t >> 5, ln = t & 31;
  const int q  = blockIdx.x*QPB + ql;
  if (ln == 0) { cnts[ql] = 0u; mc[ql] = 0u; }
  hist[ql*32 + ln] = 0u;
  if (ln < KNN) win[ql*KNN + ln] = 0ull;         // belt-and-braces: defined on any edge path
  const float4 sq = s4[q];
  __syncthreads();
  // ---- phase A: extract candidate j's (order-free compaction) ----
  uint wv[16]; int pc = 0;
#pragma unroll
  for (int u = 0; u < 4; ++u) {
    const int c = ln*4 + u;
    uint4 m4 = maskw[(size_t)c*NPTS + q];
    wv[u*4+0] = m4.x; wv[u*4+1] = m4.y; wv[u*4+2] = m4.z; wv[u*4+3] = m4.w;
    pc += __popc(m4.x) + __popc(m4.y) + __popc(m4.z) + __popc(m4.w);
  }
  int base = (int)atomicAdd(&cnts[ql], (uint)pc);
#pragma unroll
  for (int w = 0; w < 16; ++w) {
    uint bits = wv[w];
    const int jb = (ln*4 + (w >> 2))*128 + (w & 3)*32;
    while (bits) {
      int b = __builtin_ctz(bits); bits &= bits - 1;
      if (base < QCAP) jl[ql*QCAP + base] = (unsigned short)(jb + b);
      ++base;
    }
  }
  __syncthreads();
  const int cnt = min((int)cnts[ql], QCAP);
  // ---- phase B: exact keys (u64 = d2bits<<14 | j) + max class ----
  uint kmax = 0u;
  for (int u = ln; u < cnt; u += 32) {
    int j = jl[ql*QCAP + u];
    float e = d2f(sq, s4[j]);
    uint db = __float_as_uint(e);
    keys[ql*QCAP + u] = ((u64)db << 14) | (uint)j;
    kmax = max(kmax, db >> 21);
  }
#pragma unroll
  for (int m = 1; m < 32; m <<= 1) kmax = max(kmax, (uint)__shfl_xor((int)kmax, m, 32));
  for (int u = ln; u < cnt; u += 32) {
    uint cls = (uint)(keys[ql*QCAP + u] >> 35);
    uint rel = min(kmax - cls, 31u);
    atomicAdd(&hist[ql*32 + rel], 1u);
  }
  __syncthreads();
  // ---- boundary: largest r* with cum(r*) >= need; bcls = kmax - r* ----
  uint cum = hist[ql*32 + ln];
#pragma unroll
  for (int d = 1; d < 32; d <<= 1) {
    uint v = (uint)__shfl_down((int)cum, d, 32);
    if (ln + d < 32) cum += v;               // cum(ln) = sum of bins >= ln
  }
  const uint need = (uint)(cnt < KNN ? cnt : KNN);
  u64 bal = __ballot(cum >= need);
  uint half = (uint)(bal >> (((t >> 5) & 1) * 32));   // cum(0)=cnt>=need -> half != 0
  const uint rstar = 31u - (uint)__builtin_clz(half);
  const uint bcls = kmax - rstar;
  // ---- compact qualifier keys into qbuf (aliases jl; jl reads are done) ----
  __syncthreads();
  for (int u = ln; u < cnt; u += 32) {
    u64 key = keys[ql*QCAP + u];
    if ((uint)(key >> 35) <= bcls) {
      uint pos = atomicAdd(&mc[ql], 1u);
      if (pos < MCAP) qbuf[ql*MCAP + pos] = key;
    }
  }
  __syncthreads();
  const int mcnt = (int)mc[ql];
  if (mcnt <= MCAP) {
    for (int w = ln; w < mcnt; w += 32) {
      u64 key = qbuf[ql*MCAP + w];
      int rank = 0;
      for (int v = 0; v < mcnt; ++v) rank += (qbuf[ql*MCAP + v] < key) ? 1 : 0;
      if (rank < KNN) win[ql*KNN + rank] = key;
    }
  } else {
    // rare qualifier overflow: rank own qualifiers against the full key list
    for (int u = ln; u < cnt; u += 32) {
      u64 key = keys[ql*QCAP + u];
      if ((uint)(key >> 35) <= bcls) {
        int rank = 0;
        for (int v = 0; v < cnt; ++v) rank += (keys[ql*QCAP + v] < key) ? 1 : 0;
        if (rank < KNN) win[ql*KNN + rank] = key;
      }
    }
  }
  __syncthreads();
  // ---- aggregation: lane = h component, winners in rank order ----
  float sum = 0.f, mx = -FLTMAX;
#pragma unroll 1
  for (int r = 0; r < KNN; ++r) {
    u64 key = win[ql*KNN + r];
    float d2 = __uint_as_float((uint)(key >> 14));
    int j = (int)(key & 16383u);
    float w = __expf(-10.f * d2);
    float m = w * h[(size_t)j*PD + ln];
    sum += m; mx = fmaxf(mx, m);
  }
  agg[(size_t)q*64 + ln]      = sum * 0.0625f;
  agg[(size_t)q*64 + 32 + ln] = mx;
}

// ================= Fallback path (round-2, proven) =================
__global__ __launch_bounds__(256) void k2_knn_fb(
    const float4* __restrict__ s4, unsigned short* __restrict__ cand_j) {
  __shared__ float4 tile[TJF];
  __shared__ int    lbuf[256*33];
  const int t  = threadIdx.x;
  const int ib = blockIdx.x & 31;
  const int jc = blockIdx.x >> 5;
  const int jbase = jc * TJF;
#pragma unroll
  for (int g = 0; g < 4; ++g) tile[g*256 + t] = s4[jbase + g*256 + t];
  const int ia = ib*256 + t;
  const int ic = ia + 8192;
  const float4 sa = s4[ia];
  const float4 sc = s4[ic];
  __syncthreads();
  float va[KNN], vb[KNN]; int ja[KNN], jb[KNN];
#pragma unroll
  for (int q = 0; q < KNN; ++q) { va[q] = FLTMAX; ja[q] = 0; vb[q] = FLTMAX; jb[q] = 0; }
  float cma = FLTMAX, cmb = FLTMAX;
  int cpa = 0, cpb = 0, ca = 0, cb = 0;
  auto insertA = [&](float e, int jj) {
#pragma unroll
    for (int q = 0; q < KNN; ++q) if (q == cpa) { va[q] = e; ja[q] = jj; }
    cma = va[0]; cpa = 0;
#pragma unroll
    for (int q = 1; q < KNN; ++q) { if (va[q] > cma) { cma = va[q]; cpa = q; } }
  };
  auto insertB = [&](float e, int jj) {
#pragma unroll
    for (int q = 0; q < KNN; ++q) if (q == cpb) { vb[q] = e; jb[q] = jj; }
    cmb = vb[0]; cpb = 0;
#pragma unroll
    for (int q = 1; q < KNN; ++q) { if (vb[q] > cmb) { cmb = vb[q]; cpb = q; } }
  };
  auto compactA = [&]() {
    for (int u = 0; u < ca; ++u) {
      int jj = lbuf[t*33 + u];
      float e = d2f(sa, tile[jj]);
      if (e < cma) insertA(e, jj);
    }
    ca = 0;
  };
  auto compactB = [&]() {
    for (int u = 0; u < cb; ++u) {
      int jj = lbuf[t*33 + 16 + u];
      float e = d2f(sc, tile[jj]);
      if (e < cmb) insertB(e, jj);
    }
    cb = 0;
  };
  for (int ob = 0; ob < TJF/8; ++ob) {
#pragma unroll
    for (int u = 0; u < 8; ++u) {
      int jj = ob*8 + u;
      float4 p = tile[jj];
      float ea = d2f(sa, p);
      float eb = d2f(sc, p);
      if (ea < cma) { lbuf[t*33 + ca] = jj; ++ca; }
      if (eb < cmb) { lbuf[t*33 + 16 + cb] = jj; ++cb; }
    }
    if (__any(ca > 8)) compactA();
    if (__any(cb > 8)) compactB();
  }
  compactA(); compactB();
#pragma unroll
  for (int q = 0; q < KNN; ++q) {
    int c = jc*KNN + q;
    cand_j[(size_t)c*NPTS + ia] = (unsigned short)(ja[q] + jbase);
    cand_j[(size_t)c*NPTS + ic] = (unsigned short)(jb[q] + jbase);
  }
}

__global__ __launch_bounds__(256) void k3_merge_fb(
    const float4* __restrict__ s4, const float4* __restrict__ h4,
    const unsigned short* __restrict__ cand_j, float* __restrict__ agg) {
  __shared__ float le[64*67];
  __shared__ int   lj[64*67];
  const int t  = threadIdx.x;
  const int il = t & 63, tq = t >> 6;
  const int i  = blockIdx.x*64 + il;
  const float4 si = s4[i];
  float val[KNN]; int vid[KNN];
#pragma unroll
  for (int q = 0; q < KNN; ++q) { val[q] = FLTMAX; vid[q] = 0; }
  float cmax = FLTMAX; int cpos = 0;
  for (int u = 0; u < 64; ++u) {
    int c = tq*64 + u;
    int j = cand_j[(size_t)c*NPTS + i];
    float e = d2f(si, s4[j]);
    if (e < cmax) {
#pragma unroll
      for (int q = 0; q < KNN; ++q) if (q == cpos) { val[q] = e; vid[q] = j; }
      cmax = val[0]; cpos = 0;
#pragma unroll
      for (int q = 1; q < KNN; ++q) { if (val[q] > cmax) { cmax = val[q]; cpos = q; } }
    }
  }
#pragma unroll
  for (int q = 0; q < KNN; ++q) {
    le[il*67 + tq*16 + q] = val[q];
    lj[il*67 + tq*16 + q] = vid[q];
  }
  __syncthreads();
  if (t < 64) {
    float mv[KNN]; int mj[KNN];
#pragma unroll
    for (int q = 0; q < KNN; ++q) { mv[q] = FLTMAX; mj[q] = 0; }
    float cm2 = FLTMAX; int cp2 = 0;
    for (int u = 0; u < 64; ++u) {
      float e = le[t*67 + u];
      int   j = lj[t*67 + u];
      if (e < cm2) {
#pragma unroll
        for (int q = 0; q < KNN; ++q) if (q == cp2) { mv[q] = e; mj[q] = j; }
        cm2 = mv[0]; cp2 = 0;
#pragma unroll
        for (int q = 1; q < KNN; ++q) { if (mv[q] > cm2) { cm2 = mv[q]; cp2 = q; } }
      }
    }
#pragma unroll
    for (int q = 0; q < KNN; ++q) {
      le[t*67 + q] = __expf(-10.f * mv[q]);
      lj[t*67 + q] = mj[q];
    }
  }
  __syncthreads();
  float ms[8], mm[8];
#pragma unroll
  for (int p = 0; p < 8; ++p) { ms[p] = 0.f; mm[p] = -FLTMAX; }
#pragma unroll 1
  for (int q = 0; q < KNN; ++q) {
    float w = le[il*67 + q];
    int   j = lj[il*67 + q];
    float4 a = h4[(size_t)j*8 + tq*2];
    float4 b = h4[(size_t)j*8 + tq*2 + 1];
    float m0 = a.x*w, m1 = a.y*w, m2 = a.z*w, m3 = a.w*w;
    float m4 = b.x*w, m5 = b.y*w, m6 = b.z*w, m7 = b.w*w;
    ms[0] += m0; mm[0] = fmaxf(mm[0], m0);
    ms[1] += m1; mm[1] = fmaxf(mm[1], m1);
    ms[2] += m2; mm[2] = fmaxf(mm[2], m2);
    ms[3] += m3; mm[3] = fmaxf(mm[3], m3);
    ms[4] += m4; mm[4] = fmaxf(mm[4], m4);
    ms[5] += m5; mm[5] = fmaxf(mm[5], m5);
    ms[6] += m6; mm[6] = fmaxf(mm[6], m6);
    ms[7] += m7; mm[7] = fmaxf(mm[7], m7);
  }
  float4 o0 = make_float4(ms[0]*0.0625f, ms[1]*0.0625f, ms[2]*0.0625f, ms[3]*0.0625f);
  float4 o1 = make_float4(ms[4]*0.0625f, ms[5]*0.0625f, ms[6]*0.0625f, ms[7]*0.0625f);
  *(float4*)&agg[(size_t)i*64 + tq*8]      = o0;
  *(float4*)&agg[(size_t)i*64 + tq*8 + 4]  = o1;
  *(float4*)&agg[(size_t)i*64 + 32 + tq*8]     = make_float4(mm[0], mm[1], mm[2], mm[3]);
  *(float4*)&agg[(size_t)i*64 + 32 + tq*8 + 4] = make_float4(mm[4], mm[5], mm[6], mm[7]);
}

// ---------------- Kernel 4a: pack/transpose weights ----------------
__global__ __launch_bounds__(256) void k4a_wt(
    const float* __restrict__ W1, const float* __restrict__ W2, float* __restrict__ wT) {
  int idx = blockIdx.x*256 + threadIdx.x;
  if (idx >= 192*COUT) return;
  int k = idx >> 7, c = idx & 127;
  float v = (k < 128) ? W1[(size_t)c*128 + k] : W2[(size_t)c*64 + (k - 128)];
  wT[(size_t)k*COUT + c] = v;
}

// ---------------- Kernel 4: out = x@W1^T + agg@W2^T + b2 (32x128 tile, 4x4/thread) ----------
__global__ __launch_bounds__(256) void k4_out2(
    const float* __restrict__ x, const float* __restrict__ agg,
    const float* __restrict__ wT, const float* __restrict__ b2,
    float* __restrict__ out) {
  __shared__ float xa[32*192];
  const int t = threadIdx.x;
  const int row0 = blockIdx.x * 32;
#pragma unroll
  for (int g = 0; g < 4; ++g) {
    int fi = g*256 + t;
    int r = fi >> 5, c4 = fi & 31;
    *(float4*)&xa[r*192 + c4*4] = *(const float4*)&x[(size_t)(row0+r)*CIN + c4*4];
  }
#pragma unroll
  for (int g = 0; g < 2; ++g) {
    int fi = g*256 + t;
    int r = fi >> 4, c4 = fi & 15;
    *(float4*)&xa[r*192 + 128 + c4*4] = *(const float4*)&agg[(size_t)(row0+r)*64 + c4*4];
  }
  __syncthreads();
  const int c4 = t & 31;
  const int rg = t >> 5;
  float acc[4][4];
#pragma unroll
  for (int r = 0; r < 4; ++r) { acc[r][0]=0.f; acc[r][1]=0.f; acc[r][2]=0.f; acc[r][3]=0.f; }
  for (int k = 0; k < 192; k += 4) {
    float4 w0 = *(const float4*)&wT[(size_t)(k+0)*COUT + c4*4];
    float4 w1 = *(const float4*)&wT[(size_t)(k+1)*COUT + c4*4];
    float4 w2 = *(const float4*)&wT[(size_t)(k+2)*COUT + c4*4];
    float4 w3 = *(const float4*)&wT[(size_t)(k+3)*COUT + c4*4];
#pragma unroll
    for (int r = 0; r < 4; ++r) {
      float4 xv = *(const float4*)&xa[(rg*4 + r)*192 + k];
      acc[r][0] = fmaf(xv.x, w0.x, fmaf(xv.y, w1.x, fmaf(xv.z, w2.x, fmaf(xv.w, w3.x, acc[r][0]))));
      acc[r][1] = fmaf(xv.x, w0.y, fmaf(xv.y, w1.y, fmaf(xv.z, w2.y, fmaf(xv.w, w3.y, acc[r][1]))));
      acc[r][2] = fmaf(xv.x, w0.z, fmaf(xv.y, w1.z, fmaf(xv.z, w2.z, fmaf(xv.w, w3.z, acc[r][2]))));
      acc[r][3] = fmaf(xv.x, w0.w, fmaf(xv.y, w1.w, fmaf(xv.z, w2.w, fmaf(xv.w, w3.w, acc[r][3]))));
    }
  }
  float4 bias = *(const float4*)&b2[c4*4];
#pragma unroll
  for (int r = 0; r < 4; ++r) {
    float4 o = make_float4(acc[r][0]+bias.x, acc[r][1]+bias.y, acc[r][2]+bias.z, acc[r][3]+bias.w);
    *(float4*)&out[(size_t)(row0 + rg*4 + r)*COUT + c4*4] = o;
  }
}

extern "C" void kernel_launch(void* const* d_in, const int* in_sizes, int n_in,
                              void* d_out, int out_size, void* d_ws, size_t ws_size,
                              hipStream_t stream) {
  const float* x  = (const float*)d_in[0];
  const float* Ws = (const float*)d_in[1];
  const float* bs = (const float*)d_in[2];
  const float* Wh = (const float*)d_in[3];
  const float* bh = (const float*)d_in[4];
  const float* W1 = (const float*)d_in[5];
  const float* W2 = (const float*)d_in[6];
  const float* b2 = (const float*)d_in[7];
  float* out = (float*)d_out;

  char* ws = (char*)d_ws;
  float4* s4 = (float4*)(ws + WS_S4);
  float*  h  = (float*) (ws + WS_H);

  k1_proj<<<NPTS/64, 256, 0, stream>>>(x, Ws, bs, Wh, bh, s4, h);

  if (ws_size >= (size_t)WS_NEED_M) {
    float* t2  = (float*)(ws + WS_T2);
    float* agg = (float*)(ws + WS_AGG_M);
    float* wT  = (float*)(ws + WS_WT_M);
    uint*  mw  = (uint*) (ws + WS_MASK);
    k2t_thresh<<<NPTS/16, 256, 0, stream>>>(s4, t2);
    k2b_mask<<<2048, 256, 0, stream>>>(s4, t2, mw);
    k3_sel2<<<NPTS/QPB, 256, 0, stream>>>(s4, h, (const uint4*)mw, agg);
    k4a_wt<<<(192*COUT + 255)/256, 256, 0, stream>>>(W1, W2, wT);
    k4_out2<<<NPTS/32, 256, 0, stream>>>(x, agg, wT, b2, out);
  } else {
    unsigned short* cj = (unsigned short*)(ws + WS_CJ_F);
    float* agg = (float*)(ws + WS_AGG_F);
    float* wT  = (float*)(ws + WS_WT_F);
    k2_knn_fb<<<512, 256, 0, stream>>>(s4, cj);
    k3_merge_fb<<<NPTS/64, 256, 0, stream>>>(s4, (const float4*)h, cj, agg);
    k4a_wt<<<(192*COUT + 255)/256, 256, 0, stream>>>(W1, W2, wT);
    k4_out2<<<NPTS/32, 256, 0, stream>>>(x, agg, wT, b2, out);
  }
}